// Round 1
// baseline (241.756 us; speedup 1.0000x reference)
//
#include <hip/hip_runtime.h>

// Attention_13632226198096: B=4, S=2048, D=1024 fp32 single-head attention.
// Strategy: bf16 MFMA GEMMs (m97-style 128x128 tile, global_load_lds staging),
// fp32 softmax. q=x@Wq^T+bq etc; sim=q@k^T/32; P=softmax(sim); out=P@v.
// ws layout: xb | w3 | q | k | vt | scores | P   (v_plain staged in scores region)

typedef unsigned short ushort_t;
typedef __bf16 bf16x8 __attribute__((ext_vector_type(8)));
typedef float f32x4 __attribute__((ext_vector_type(4)));

__device__ __forceinline__ unsigned short f2bf(float f) {
  unsigned u = __builtin_bit_cast(unsigned, f);
  u += 0x7fffu + ((u >> 16) & 1u);
  return (unsigned short)(u >> 16);
}

// ---------------------------------------------------------------------------
// C[z][M,N] = scale * (A[z][M,K] @ B[z][N,K]^T) + bias[col]
// 128x128 tile, BK=64, 256 threads (4 waves, each 64x64 of 16x16x32 MFMA).
// ---------------------------------------------------------------------------
template<int OUT_BF16>
__global__ __launch_bounds__(256)
void gemm_bt(const ushort_t* __restrict__ A, long long sAz,
             const ushort_t* __restrict__ Bm, long long sBz,
             void* __restrict__ Cv, long long sCz,
             int N, int K, float scale, const float* __restrict__ bias)
{
  const int z = blockIdx.z;
  A  += (long long)z * sAz;
  Bm += (long long)z * sBz;

  const int row0 = blockIdx.y * 128;
  const int col0 = blockIdx.x * 128;

  __shared__ ushort_t smA[128 * 64] __attribute__((aligned(16)));
  __shared__ ushort_t smB[128 * 64] __attribute__((aligned(16)));

  const int tid  = threadIdx.x;
  const int wave = tid >> 6;
  const int lane = tid & 63;
  const int wr = (wave >> 1) * 64;   // wave row offset in tile
  const int wc = (wave & 1) * 64;    // wave col offset in tile

  f32x4 acc[4][4];
#pragma unroll
  for (int m = 0; m < 4; ++m)
#pragma unroll
    for (int n = 0; n < 4; ++n)
#pragma unroll
      for (int j = 0; j < 4; ++j) acc[m][n][j] = 0.f;

  // staging: thread t loads 16B from row (t>>3), k-offset (t&7)*8
  const long long arow = row0 + (tid >> 3);
  const long long brow = col0 + (tid >> 3);
  const int kcol = (tid & 7) * 8;
  const ushort_t* ag = A  + arow * K + kcol;
  const ushort_t* bg = Bm + brow * K + kcol;
  // wave-uniform LDS dest base (lane*16B appended by HW)
  ushort_t* ldsA = &smA[(wave * 8) * 64];
  ushort_t* ldsB = &smB[(wave * 8) * 64];

  for (int k0 = 0; k0 < K; k0 += 64) {
#pragma unroll
    for (int i = 0; i < 4; ++i) {
      __builtin_amdgcn_global_load_lds(
          (const __attribute__((address_space(1))) void*)(ag + (long long)i * 32 * K + k0),
          (__attribute__((address_space(3))) void*)(ldsA + i * 32 * 64), 16, 0, 0);
      __builtin_amdgcn_global_load_lds(
          (const __attribute__((address_space(1))) void*)(bg + (long long)i * 32 * K + k0),
          (__attribute__((address_space(3))) void*)(ldsB + i * 32 * 64), 16, 0, 0);
    }
    __syncthreads();   // drains vmcnt before reads
#pragma unroll
    for (int kk = 0; kk < 2; ++kk) {
      const int klo = kk * 32 + (lane >> 4) * 8;
      bf16x8 af[4], bfv[4];
#pragma unroll
      for (int m = 0; m < 4; ++m)
        af[m] = *(const bf16x8*)&smA[(wr + m * 16 + (lane & 15)) * 64 + klo];
#pragma unroll
      for (int n = 0; n < 4; ++n)
        bfv[n] = *(const bf16x8*)&smB[(wc + n * 16 + (lane & 15)) * 64 + klo];
#pragma unroll
      for (int m = 0; m < 4; ++m)
#pragma unroll
        for (int n = 0; n < 4; ++n)
          acc[m][n] = __builtin_amdgcn_mfma_f32_16x16x32_bf16(af[m], bfv[n], acc[m][n], 0, 0, 0);
    }
    __syncthreads();   // before next-tile overwrite
  }

  // epilogue: C/D layout col=lane&15, row=(lane>>4)*4+j   [m89-verified]
  const int r4 = (lane >> 4) * 4;
  const int cl = lane & 15;
#pragma unroll
  for (int m = 0; m < 4; ++m) {
#pragma unroll
    for (int n = 0; n < 4; ++n) {
      const int cg = col0 + wc + n * 16 + cl;
      const float badd = bias ? bias[cg] : 0.f;
#pragma unroll
      for (int j = 0; j < 4; ++j) {
        const long long rg = row0 + wr + m * 16 + r4 + j;
        const float v = acc[m][n][j] * scale + badd;
        if (OUT_BF16) {
          ((ushort_t*)Cv)[(long long)z * sCz + rg * N + cg] = f2bf(v);
        } else {
          ((float*)Cv)[(long long)z * sCz + rg * N + cg] = v;
        }
      }
    }
  }
}

// ---------------------------------------------------------------------------
// fp32 -> bf16 cast, vectorized (n multiple of 4)
// ---------------------------------------------------------------------------
__global__ __launch_bounds__(256)
void cast_f32_bf16(const float* __restrict__ in, ushort_t* __restrict__ out, long long n)
{
  long long i = ((long long)blockIdx.x * blockDim.x + threadIdx.x) * 4;
  const long long stride = (long long)gridDim.x * blockDim.x * 4;
  for (; i < n; i += stride) {
    const float4 v = *(const float4*)&in[i];
    ushort4 o;
    o.x = f2bf(v.x); o.y = f2bf(v.y); o.z = f2bf(v.z); o.w = f2bf(v.w);
    *(ushort4*)&out[i] = o;
  }
}

// ---------------------------------------------------------------------------
// bf16 transpose per batch: in[z][rows][cols] -> out[z][cols][rows]
// ---------------------------------------------------------------------------
__global__ __launch_bounds__(256)
void transpose_bf16(const ushort_t* __restrict__ in, ushort_t* __restrict__ out,
                    int rows, int cols, long long sIn, long long sOut)
{
  __shared__ ushort_t t[64][65];
  in  += (long long)blockIdx.z * sIn;
  out += (long long)blockIdx.z * sOut;
  const int r0 = blockIdx.y * 64;   // source row block
  const int c0 = blockIdx.x * 64;   // source col block
  const int tx = threadIdx.x & 15, ty = threadIdx.x >> 4;
#pragma unroll
  for (int r = 0; r < 4; ++r) {
    const ushort4 v = *(const ushort4*)&in[(long long)(r0 + ty * 4 + r) * cols + c0 + tx * 4];
    t[ty * 4 + r][tx * 4 + 0] = v.x;
    t[ty * 4 + r][tx * 4 + 1] = v.y;
    t[ty * 4 + r][tx * 4 + 2] = v.z;
    t[ty * 4 + r][tx * 4 + 3] = v.w;
  }
  __syncthreads();
#pragma unroll
  for (int r = 0; r < 4; ++r) {
    const int d = ty * 4 + r;
    ushort4 v;
    v.x = t[tx * 4 + 0][d];
    v.y = t[tx * 4 + 1][d];
    v.z = t[tx * 4 + 2][d];
    v.w = t[tx * 4 + 3][d];
    *(ushort4*)&out[(long long)(c0 + d) * rows + r0 + tx * 4] = v;
  }
}

// ---------------------------------------------------------------------------
// row softmax over 2048 fp32 -> bf16, one block (256 thr) per row
// ---------------------------------------------------------------------------
__global__ __launch_bounds__(256)
void softmax2048(const float* __restrict__ Sc, ushort_t* __restrict__ P)
{
  const long long row = blockIdx.x;
  const float* s = Sc + row * 2048;
  const int tid = threadIdx.x;
  const int wave = tid >> 6, lane = tid & 63;

  const float4 a = *(const float4*)&s[tid * 4];
  const float4 b = *(const float4*)&s[1024 + tid * 4];
  float m = fmaxf(fmaxf(fmaxf(a.x, a.y), fmaxf(a.z, a.w)),
                  fmaxf(fmaxf(b.x, b.y), fmaxf(b.z, b.w)));
#pragma unroll
  for (int off = 32; off > 0; off >>= 1) m = fmaxf(m, __shfl_xor(m, off));
  __shared__ float redm[4], reds[4];
  if (lane == 0) redm[wave] = m;
  __syncthreads();
  m = fmaxf(fmaxf(redm[0], redm[1]), fmaxf(redm[2], redm[3]));

  float e[8];
  e[0] = __expf(a.x - m); e[1] = __expf(a.y - m); e[2] = __expf(a.z - m); e[3] = __expf(a.w - m);
  e[4] = __expf(b.x - m); e[5] = __expf(b.y - m); e[6] = __expf(b.z - m); e[7] = __expf(b.w - m);
  float sum = ((e[0] + e[1]) + (e[2] + e[3])) + ((e[4] + e[5]) + (e[6] + e[7]));
#pragma unroll
  for (int off = 32; off > 0; off >>= 1) sum += __shfl_xor(sum, off);
  if (lane == 0) reds[wave] = sum;
  __syncthreads();
  sum = (reds[0] + reds[1]) + (reds[2] + reds[3]);
  const float inv = 1.0f / sum;

  ushort4 o;
  o.x = f2bf(e[0] * inv); o.y = f2bf(e[1] * inv); o.z = f2bf(e[2] * inv); o.w = f2bf(e[3] * inv);
  *(ushort4*)&P[row * 2048 + tid * 4] = o;
  o.x = f2bf(e[4] * inv); o.y = f2bf(e[5] * inv); o.z = f2bf(e[6] * inv); o.w = f2bf(e[7] * inv);
  *(ushort4*)&P[row * 2048 + 1024 + tid * 4] = o;
}

// ---------------------------------------------------------------------------
extern "C" void kernel_launch(void* const* d_in, const int* in_sizes, int n_in,
                              void* d_out, int out_size, void* d_ws, size_t ws_size,
                              hipStream_t stream)
{
  constexpr int B = 4, S = 2048, D = 1024;
  constexpr long long MT = (long long)B * S;        // 8192 tokens
  constexpr long long SD = (long long)S * D;        // per-batch q/k/v elems
  constexpr long long SS = (long long)S * S;        // per-batch score elems

  const float* x  = (const float*)d_in[0];
  const float* Wq = (const float*)d_in[1];
  const float* bq = (const float*)d_in[2];
  const float* Wk = (const float*)d_in[3];
  const float* bk = (const float*)d_in[4];
  const float* Wv = (const float*)d_in[5];
  const float* bv = (const float*)d_in[6];
  float* out = (float*)d_out;

  char* p = (char*)d_ws;
  ushort_t* xb = (ushort_t*)p;           p += MT * D * 2;       // 16.78 MB
  ushort_t* w3 = (ushort_t*)p;           p += 3LL * D * D * 2;  //  6.29 MB
  ushort_t* q  = (ushort_t*)p;           p += MT * D * 2;
  ushort_t* k  = (ushort_t*)p;           p += MT * D * 2;
  ushort_t* vt = (ushort_t*)p;           p += MT * D * 2;       // [B][D][S]
  float*    scores = (float*)p;                                  // nb*S*S fp32
  ushort_t* vplain = (ushort_t*)scores;                          // staged pre-transpose

  // batched (one QK/softmax/PV over all 4 batches) if ws fits, else per-batch
  const size_t base = (size_t)(p - (char*)d_ws);
  const int nb = (ws_size >= base + (size_t)B * SS * 4 + (size_t)B * SS * 2) ? B : 1;
  ushort_t* P = (ushort_t*)(scores + (long long)nb * SS);

  // 1) casts (biases stay fp32, consumed by GEMM epilogue)
  cast_f32_bf16<<<2048, 256, 0, stream>>>(x, xb, MT * D);
  cast_f32_bf16<<<1024, 256, 0, stream>>>(Wq, w3 + 0LL * D * D, (long long)D * D);
  cast_f32_bf16<<<1024, 256, 0, stream>>>(Wk, w3 + 1LL * D * D, (long long)D * D);
  cast_f32_bf16<<<1024, 256, 0, stream>>>(Wv, w3 + 2LL * D * D, (long long)D * D);

  // 2) projections: [8192,1024] = xb @ W^T + b   (W already [N,K] row-major)
  {
    dim3 g(D / 128, MT / 128, 1);
    gemm_bt<1><<<g, 256, 0, stream>>>(xb, 0, w3 + 0LL * D * D, 0, q,      0, D, D, 1.f, bq);
    gemm_bt<1><<<g, 256, 0, stream>>>(xb, 0, w3 + 1LL * D * D, 0, k,      0, D, D, 1.f, bk);
    gemm_bt<1><<<g, 256, 0, stream>>>(xb, 0, w3 + 2LL * D * D, 0, vplain, 0, D, D, 1.f, bv);
  }

  // 3) v -> v^T per batch: [S][D] -> [D][S]
  {
    dim3 g(D / 64, S / 64, B);
    transpose_bf16<<<g, 256, 0, stream>>>(vplain, vt, S, D, SD, SD);
  }

  // 4) attention, nb batches per round
  const float scale = 0.03125f;  // 1/sqrt(1024)
  for (int b0 = 0; b0 < B; b0 += nb) {
    dim3 gqk(S / 128, S / 128, nb);
    gemm_bt<0><<<gqk, 256, 0, stream>>>(q + b0 * SD, SD, k + b0 * SD, SD,
                                        scores, SS, S, D, scale, nullptr);
    softmax2048<<<nb * S, 256, 0, stream>>>(scores, P);
    dim3 gpv(D / 128, S / 128, nb);
    gemm_bt<0><<<gpv, 256, 0, stream>>>(P, SS, vt + b0 * (long long)D * S, (long long)D * S,
                                        out + b0 * SD, SD, D, S, 1.f, nullptr);
  }
}

// Round 2
// 229.834 us; speedup vs baseline: 1.0519x; 1.0519x over previous
//
#include <hip/hip_runtime.h>

// Attention_13632226198096: B=4, S=2048, D=1024 fp32 single-head attention.
// Round 2: 256x256-tile 8-phase bf16 MFMA GEMM (m201-style: LDS XOR swizzle,
// counted vmcnt, setprio, raw s_barrier), fused QKV projection (N=3072).
// Pipeline: cast_x | prep_w -> proj(8192x3072x1024) -> v-transpose ->
//           QK^T (2048x2048x1024, z=4) -> softmax -> PV (2048x1024x2048, z=4)

typedef unsigned short ushort_t;
typedef __bf16 bf16x8 __attribute__((ext_vector_type(8)));
typedef float f32x4 __attribute__((ext_vector_type(4)));

__device__ __forceinline__ unsigned short f2bf(float f) {
  unsigned u = __builtin_bit_cast(unsigned, f);
  u += 0x7fffu + ((u >> 16) & 1u);
  return (unsigned short)(u >> 16);
}

// ---------------------------------------------------------------------------
// C[z][M,N] = scale*(A[z] @ B[z]^T) + bias[col]; A[M,K] lda, B[N,K] ldb.
// BM=BN=256, BK=64, 512 threads = 8 waves (2Mx4N), per-wave out 128x64.
// LDS: 8 half-slots [dbuf][A/B][half] of 128x64 bf16 = 128 KiB, st_16x32 swz.
// Phases per K-tile: {k0,n01},{k0,n23},{k1,n01},{k1,n23}; 16 MFMA each.
// Staging rotation: ph1:B0(t+1) ph2:B1(t+1) ph3:A0(t+2) ph4:A1(t+2);
// vmcnt(4) at tile boundary (2 halves in flight), vmcnt(0) only at t=NT-2.
// ---------------------------------------------------------------------------
template<int OUT_BF16>
__global__ __launch_bounds__(512, 1)
void gemm8p(const ushort_t* __restrict__ A, long long sAz, int lda,
            const ushort_t* __restrict__ Bm, long long sBz, int ldb,
            void* __restrict__ Cv, long long sCz, int ldc,
            int K, float scale, const float* __restrict__ bias)
{
  __shared__ ushort_t lds_[8][8192] __attribute__((aligned(16)));

  const int z = blockIdx.z;
  const ushort_t* Ab = A  + (long long)z * sAz + (long long)blockIdx.y * 256 * lda;
  const ushort_t* Bb = Bm + (long long)z * sBz + (long long)blockIdx.x * 256 * ldb;

  const int tid  = threadIdx.x;
  const int wid  = tid >> 6;
  const int lane = tid & 63;
  const int wr   = wid >> 2;      // 0..1  (row half)
  const int wc   = wid & 3;       // 0..3  (col quarter)
  const int l15  = lane & 15;
  // swizzled k-offset: (lane>>4)*8 with bit4 XORed by row-bit2 (l15&4)
  const int kx   = (((lane >> 4) * 8) ^ ((l15 & 4) << 2));

  // staging source mapping (pre-swizzled global address, linear LDS dest)
  const int cidx0 = wid * 128 + lane;
  const int cidx1 = wid * 128 + 64 + lane;
  const int lidx0 = cidx0 ^ (((cidx0 >> 5) & 1) << 1);
  const int lidx1 = cidx1 ^ (((cidx1 >> 5) & 1) << 1);
  const int srow0 = lidx0 >> 3, scol0 = (lidx0 & 7) * 8;
  const int srow1 = lidx1 >> 3, scol1 = (lidx1 & 7) * 8;
  const int loff0 = (wid * 128) * 8;        // elems, wave-uniform
  const int loff1 = (wid * 128 + 64) * 8;

  auto stg = [&](int mat, int q, int h, int t) {
    const ushort_t* g = (mat == 0 ? Ab : Bb);
    const int ld = (mat == 0 ? lda : ldb);
    const ushort_t* g0 = g + (long long)(h * 128 + srow0) * ld + t * 64 + scol0;
    const ushort_t* g1 = g + (long long)(h * 128 + srow1) * ld + t * 64 + scol1;
    ushort_t* d = &lds_[q * 4 + mat * 2 + h][0];
    __builtin_amdgcn_global_load_lds((const __attribute__((address_space(1))) void*)g0,
        (__attribute__((address_space(3))) void*)(d + loff0), 16, 0, 0);
    __builtin_amdgcn_global_load_lds((const __attribute__((address_space(1))) void*)g1,
        (__attribute__((address_space(3))) void*)(d + loff1), 16, 0, 0);
  };

  f32x4 acc[8][4];
#pragma unroll
  for (int m = 0; m < 8; ++m)
#pragma unroll
    for (int n = 0; n < 4; ++n)
#pragma unroll
      for (int j = 0; j < 4; ++j) acc[m][n][j] = 0.f;

  // prologue: A0(0) A1(0) B0(0) B1(0) A0(1) A1(1); wait tile0 landed (4 in flight)
  stg(0, 0, 0, 0); stg(0, 0, 1, 0);
  stg(1, 0, 0, 0); stg(1, 0, 1, 0);
  stg(0, 1, 0, 1); stg(0, 1, 1, 1);
  asm volatile("s_waitcnt vmcnt(4)" ::: "memory");
  __builtin_amdgcn_s_barrier();

  const int NT = K >> 6;
  bf16x8 af[8], bf2[2];

  for (int t = 0; t < NT; ++t) {
    const int q = t & 1;
    const ushort_t* Al = &lds_[q * 4 + wr][0];
    const ushort_t* Bl = &lds_[q * 4 + 2 + (wc >> 1)][0] + (wc & 1) * 64 * 64;

    // ---- phase 1: kslice 0, n0-1
#pragma unroll
    for (int m = 0; m < 8; ++m) af[m]  = *(const bf16x8*)(Al + (m * 16 + l15) * 64 + kx);
#pragma unroll
    for (int n = 0; n < 2; ++n) bf2[n] = *(const bf16x8*)(Bl + (n * 16 + l15) * 64 + kx);
    if (t + 1 < NT) stg(1, (t + 1) & 1, 0, t + 1);
    __builtin_amdgcn_s_barrier();
    __builtin_amdgcn_s_setprio(1);
#pragma unroll
    for (int m = 0; m < 8; ++m)
#pragma unroll
      for (int n = 0; n < 2; ++n)
        acc[m][n] = __builtin_amdgcn_mfma_f32_16x16x32_bf16(af[m], bf2[n], acc[m][n], 0, 0, 0);
    __builtin_amdgcn_s_setprio(0);
    __builtin_amdgcn_s_barrier();

    // ---- phase 2: kslice 0, n2-3 (A frags reused)
#pragma unroll
    for (int n = 0; n < 2; ++n) bf2[n] = *(const bf16x8*)(Bl + ((n + 2) * 16 + l15) * 64 + kx);
    if (t + 1 < NT) stg(1, (t + 1) & 1, 1, t + 1);
    __builtin_amdgcn_s_barrier();
    __builtin_amdgcn_s_setprio(1);
#pragma unroll
    for (int m = 0; m < 8; ++m)
#pragma unroll
      for (int n = 0; n < 2; ++n)
        acc[m][n + 2] = __builtin_amdgcn_mfma_f32_16x16x32_bf16(af[m], bf2[n], acc[m][n + 2], 0, 0, 0);
    __builtin_amdgcn_s_setprio(0);
    __builtin_amdgcn_s_barrier();

    // ---- phase 3: kslice 1, n0-1
#pragma unroll
    for (int m = 0; m < 8; ++m) af[m]  = *(const bf16x8*)(Al + (m * 16 + l15) * 64 + 32 + kx);
#pragma unroll
    for (int n = 0; n < 2; ++n) bf2[n] = *(const bf16x8*)(Bl + (n * 16 + l15) * 64 + 32 + kx);
    if (t + 2 < NT) stg(0, t & 1, 0, t + 2);
    __builtin_amdgcn_s_barrier();
    __builtin_amdgcn_s_setprio(1);
#pragma unroll
    for (int m = 0; m < 8; ++m)
#pragma unroll
      for (int n = 0; n < 2; ++n)
        acc[m][n] = __builtin_amdgcn_mfma_f32_16x16x32_bf16(af[m], bf2[n], acc[m][n], 0, 0, 0);
    __builtin_amdgcn_s_setprio(0);
    __builtin_amdgcn_s_barrier();

    // ---- phase 4: kslice 1, n2-3
#pragma unroll
    for (int n = 0; n < 2; ++n) bf2[n] = *(const bf16x8*)(Bl + ((n + 2) * 16 + l15) * 64 + 32 + kx);
    if (t + 2 < NT) stg(0, t & 1, 1, t + 2);
    __builtin_amdgcn_s_barrier();
    __builtin_amdgcn_s_setprio(1);
#pragma unroll
    for (int m = 0; m < 8; ++m)
#pragma unroll
      for (int n = 0; n < 2; ++n)
        acc[m][n + 2] = __builtin_amdgcn_mfma_f32_16x16x32_bf16(af[m], bf2[n], acc[m][n + 2], 0, 0, 0);
    __builtin_amdgcn_s_setprio(0);
    if (t < NT - 2)       asm volatile("s_waitcnt vmcnt(4)" ::: "memory");
    else if (t == NT - 2) asm volatile("s_waitcnt vmcnt(0)" ::: "memory");
    __builtin_amdgcn_s_barrier();
  }

  // epilogue: C/D layout col=lane&15, row=(lane>>4)*4+j
  const int r4 = (lane >> 4) * 4;
  const long long crow0 = (long long)blockIdx.y * 256 + wr * 128;
  const int ccol0 = blockIdx.x * 256 + wc * 64;
#pragma unroll
  for (int n = 0; n < 4; ++n) {
    const int cg = ccol0 + n * 16 + l15;
    const float badd = bias ? bias[cg] : 0.f;
#pragma unroll
    for (int m = 0; m < 8; ++m)
#pragma unroll
      for (int j = 0; j < 4; ++j) {
        const long long rg = crow0 + m * 16 + r4 + j;
        const float v = acc[m][n][j] * scale + badd;
        if (OUT_BF16) ((ushort_t*)Cv)[(long long)z * sCz + rg * ldc + cg] = f2bf(v);
        else          ((float*)Cv)[(long long)z * sCz + rg * ldc + cg] = v;
      }
  }
}

// ---------------------------------------------------------------------------
__global__ __launch_bounds__(256)
void cast_f32_bf16(const float* __restrict__ in, ushort_t* __restrict__ out, long long n)
{
  long long i = ((long long)blockIdx.x * blockDim.x + threadIdx.x) * 4;
  const long long stride = (long long)gridDim.x * blockDim.x * 4;
  for (; i < n; i += stride) {
    const float4 v = *(const float4*)&in[i];
    ushort4 o;
    o.x = f2bf(v.x); o.y = f2bf(v.y); o.z = f2bf(v.z); o.w = f2bf(v.w);
    *(ushort4*)&out[i] = o;
  }
}

// cast 3 weight matrices into concatenated w3 [3072][1024] + bias concat [3072]
__global__ __launch_bounds__(256)
void prep_w(const float* __restrict__ Wq, const float* __restrict__ Wk,
            const float* __restrict__ Wv, const float* __restrict__ bq,
            const float* __restrict__ bk, const float* __restrict__ bv,
            ushort_t* __restrict__ w3, float* __restrict__ bcat)
{
  const int which = blockIdx.x >> 10;
  const float* W = (which == 0) ? Wq : (which == 1) ? Wk : Wv;
  const long long i = ((long long)(blockIdx.x & 1023) * 256 + threadIdx.x) * 4;
  const float4 v = *(const float4*)&W[i];
  ushort4 o;
  o.x = f2bf(v.x); o.y = f2bf(v.y); o.z = f2bf(v.z); o.w = f2bf(v.w);
  *(ushort4*)&w3[(long long)which * 1024 * 1024 + i] = o;
  const int g = blockIdx.x * 256 + threadIdx.x;
  if (g < 3072) bcat[g] = (g < 1024) ? bq[g] : (g < 2048) ? bk[g - 1024] : bv[g - 2048];
}

// bf16 transpose per batch: in[z][rows][ldIn-strided, cols] -> out[z][cols][rows]
__global__ __launch_bounds__(256)
void transpose_bf16(const ushort_t* __restrict__ in, ushort_t* __restrict__ out,
                    int rows, int cols, int ldIn, long long sIn, long long sOut)
{
  __shared__ ushort_t t[64][65];
  in  += (long long)blockIdx.z * sIn;
  out += (long long)blockIdx.z * sOut;
  const int r0 = blockIdx.y * 64;
  const int c0 = blockIdx.x * 64;
  const int tx = threadIdx.x & 15, ty = threadIdx.x >> 4;
#pragma unroll
  for (int r = 0; r < 4; ++r) {
    const ushort4 v = *(const ushort4*)&in[(long long)(r0 + ty * 4 + r) * ldIn + c0 + tx * 4];
    t[ty * 4 + r][tx * 4 + 0] = v.x;
    t[ty * 4 + r][tx * 4 + 1] = v.y;
    t[ty * 4 + r][tx * 4 + 2] = v.z;
    t[ty * 4 + r][tx * 4 + 3] = v.w;
  }
  __syncthreads();
#pragma unroll
  for (int r = 0; r < 4; ++r) {
    const int d = ty * 4 + r;
    ushort4 v;
    v.x = t[tx * 4 + 0][d];
    v.y = t[tx * 4 + 1][d];
    v.z = t[tx * 4 + 2][d];
    v.w = t[tx * 4 + 3][d];
    *(ushort4*)&out[(long long)(c0 + d) * rows + r0 + tx * 4] = v;
  }
}

// row softmax over 2048 fp32 -> bf16, one block per row
__global__ __launch_bounds__(256)
void softmax2048(const float* __restrict__ Sc, ushort_t* __restrict__ P)
{
  const long long row = blockIdx.x;
  const float* s = Sc + row * 2048;
  const int tid = threadIdx.x;
  const int wave = tid >> 6, lane = tid & 63;

  const float4 a = *(const float4*)&s[tid * 4];
  const float4 b = *(const float4*)&s[1024 + tid * 4];
  float m = fmaxf(fmaxf(fmaxf(a.x, a.y), fmaxf(a.z, a.w)),
                  fmaxf(fmaxf(b.x, b.y), fmaxf(b.z, b.w)));
#pragma unroll
  for (int off = 32; off > 0; off >>= 1) m = fmaxf(m, __shfl_xor(m, off));
  __shared__ float redm[4], reds[4];
  if (lane == 0) redm[wave] = m;
  __syncthreads();
  m = fmaxf(fmaxf(redm[0], redm[1]), fmaxf(redm[2], redm[3]));

  float e[8];
  e[0] = __expf(a.x - m); e[1] = __expf(a.y - m); e[2] = __expf(a.z - m); e[3] = __expf(a.w - m);
  e[4] = __expf(b.x - m); e[5] = __expf(b.y - m); e[6] = __expf(b.z - m); e[7] = __expf(b.w - m);
  float sum = ((e[0] + e[1]) + (e[2] + e[3])) + ((e[4] + e[5]) + (e[6] + e[7]));
#pragma unroll
  for (int off = 32; off > 0; off >>= 1) sum += __shfl_xor(sum, off);
  if (lane == 0) reds[wave] = sum;
  __syncthreads();
  sum = (reds[0] + reds[1]) + (reds[2] + reds[3]);
  const float inv = 1.0f / sum;

  ushort4 o;
  o.x = f2bf(e[0] * inv); o.y = f2bf(e[1] * inv); o.z = f2bf(e[2] * inv); o.w = f2bf(e[3] * inv);
  *(ushort4*)&P[row * 2048 + tid * 4] = o;
  o.x = f2bf(e[4] * inv); o.y = f2bf(e[5] * inv); o.z = f2bf(e[6] * inv); o.w = f2bf(e[7] * inv);
  *(ushort4*)&P[row * 2048 + 1024 + tid * 4] = o;
}

// ---------------------------------------------------------------------------
extern "C" void kernel_launch(void* const* d_in, const int* in_sizes, int n_in,
                              void* d_out, int out_size, void* d_ws, size_t ws_size,
                              hipStream_t stream)
{
  constexpr int B = 4, S = 2048, D = 1024;
  constexpr long long MT = (long long)B * S;        // 8192 tokens
  constexpr long long SD = (long long)S * D;
  constexpr long long SS = (long long)S * S;

  const float* x  = (const float*)d_in[0];
  const float* Wq = (const float*)d_in[1];
  const float* bq = (const float*)d_in[2];
  const float* Wk = (const float*)d_in[3];
  const float* bk = (const float*)d_in[4];
  const float* Wv = (const float*)d_in[5];
  const float* bv = (const float*)d_in[6];
  float* out = (float*)d_out;

  // ws layout (bytes), with xb/w3/bcat overlapping the later scores region:
  //   qkv   @ 0          : 8192*3072*2  = 50331648
  //   vt    @ 50331648   : 4*1024*2048*2 = 16777216
  //   scores@ 67108864   : 8192*2048*4  = 67108864
  //   P     @ 134217728  : 8192*2048*2  = 33554432   (end 167772160)
  //   xb    @ 67108864   : 16777216   (dead after proj)
  //   w3    @ 83886080   : 6291456    (dead after proj)
  //   bcat  @ 90177536   : 12288      (dead after proj)
  char* base = (char*)d_ws;
  ushort_t* qkv    = (ushort_t*)(base);
  ushort_t* vt     = (ushort_t*)(base + 50331648);
  float*    scores = (float*)   (base + 67108864);
  ushort_t* P      = (ushort_t*)(base + 134217728);
  ushort_t* xb     = (ushort_t*)(base + 67108864);
  ushort_t* w3     = (ushort_t*)(base + 83886080);
  float*    bcat   = (float*)   (base + 90177536);

  // 1) casts
  cast_f32_bf16<<<2048, 256, 0, stream>>>(x, xb, MT * D);
  prep_w<<<3072, 256, 0, stream>>>(Wq, Wk, Wv, bq, bk, bv, w3, bcat);

  // 2) fused QKV projection: [8192,3072] = xb @ w3^T + bcat
  gemm8p<1><<<dim3(12, 32, 1), 512, 0, stream>>>(
      xb, 0, D, w3, 0, D, qkv, 0, 3072, D, 1.f, bcat);

  // 3) v -> v^T per batch: qkv cols 2048..3071 -> vt [4][1024][2048]
  transpose_bf16<<<dim3(16, 32, 4), 256, 0, stream>>>(
      qkv + 2048, vt, S, D, 3072, (long long)S * 3072, (long long)D * S);

  // 4) QK^T: scores[z] = (q @ k^T) / 32
  gemm8p<0><<<dim3(8, 8, 4), 512, 0, stream>>>(
      qkv, (long long)S * 3072, 3072,
      qkv + 1024, (long long)S * 3072, 3072,
      scores, SS, S, D, 0.03125f, nullptr);

  // 5) softmax rows
  softmax2048<<<MT, 256, 0, stream>>>(scores, P);

  // 6) PV: out[z] = P @ v  (= P @ vt^T)
  gemm8p<0><<<dim3(4, 8, 4), 512, 0, stream>>>(
      P, SS, S, vt, (long long)D * S, S,
      out, SD, D, S, 1.f, nullptr);
}

// Round 3
// 194.275 us; speedup vs baseline: 1.2444x; 1.1830x over previous
//
#include <hip/hip_runtime.h>

// Attention_13632226198096: B=4, S=2048, D=1024 fp32 single-head attention.
// Round 3: 8-phase bf16 MFMA GEMM + XCD-aware 4x2-rect swizzle (T1),
// contiguous q/k buffers (proj epilogue scatter), BM template {128,256}
// so PV/proj fill all 256 CUs. fp32 softmax.

typedef unsigned short ushort_t;
typedef __bf16 bf16x8 __attribute__((ext_vector_type(8)));
typedef float f32x4 __attribute__((ext_vector_type(4)));

__device__ __forceinline__ unsigned short f2bf(float f) {
  unsigned u = __builtin_bit_cast(unsigned, f);
  u += 0x7fffu + ((u >> 16) & 1u);
  return (unsigned short)(u >> 16);
}

// ---------------------------------------------------------------------------
// C = scale*(A @ B^T) + bias[col]; A[M,K] lda, B[N,K] ldb. BN=256, BK=64.
// 512 thr = 8 waves (2M x 4N); per-wave out (BM/2) x 64.
// LDS dbuf x {A 2 halves, B 2 halves}, st_16x32 XOR swizzle (bit4 ^ row-bit2).
// 4 phases/K-tile: {k0,mh0+allB},{k0,mh1},{k1,mh0+B},{k1,mh1}; counted vmcnt.
// Staging: ph1 B0(t+1), ph2 B1(t+1), ph4 A0+A1(t+2); vmcnt(2*SWA) at tile end.
// MODE 0: fp32 C0; 1: bf16 C0; 2: qkv column-split bf16 (C0/C1/C2, ldc 1024).
// Grid must satisfy gx%4==0, gy%2==0, (gx*gy)%64==0 (XCD swizzle).
// ---------------------------------------------------------------------------
template<int BM, int MODE>
__global__ __launch_bounds__(512, 1)
void gemm8p(const ushort_t* __restrict__ A, long long sAz, int lda,
            const ushort_t* __restrict__ Bm, long long sBz, int ldb,
            void* __restrict__ C0, void* __restrict__ C1, void* __restrict__ C2,
            long long sCz, int ldc, int K, float scale, const float* __restrict__ bias)
{
  constexpr int MF  = BM / 32;        // m-frags per wave (8 or 4)
  constexpr int MH  = MF / 2;         // per phase
  constexpr int AH  = (BM / 2) * 64;  // elems per A half-slot
  constexpr int BH  = 128 * 64;
  constexpr int BUF = 2 * AH + 2 * BH;
  constexpr int SWA = AH / 4096;      // global_load_lds per wave per A-half (1|2)
  __shared__ ushort_t lds_[2 * BUF] __attribute__((aligned(16)));

  // XCD-aware bijective swizzle: 4x2 block rects, rect-contiguous per XCD
  const int gx = gridDim.x;
  const int lin = blockIdx.y * gx + blockIdx.x;
  const int nwg = gx * gridDim.y;
  const int xcd = lin & 7, pos = lin >> 3;
  const int nrx = gx >> 2;
  const int rect = xcd * (nwg >> 6) + (pos >> 3);
  const int p8 = pos & 7;
  const int bx = (rect % nrx) * 4 + (p8 & 3);
  const int by = (rect / nrx) * 2 + (p8 >> 2);

  const int z = blockIdx.z;
  const ushort_t* Ab = A  + (long long)z * sAz + (long long)by * BM  * lda;
  const ushort_t* Bb = Bm + (long long)z * sBz + (long long)bx * 256 * ldb;

  const int tid = threadIdx.x, wid = tid >> 6, lane = tid & 63;
  const int wr = wid >> 2, wc = wid & 3;
  const int l15 = lane & 15;
  const int kx   = ((lane >> 4) * 8) ^ ((l15 & 4) << 2);     // read swizzle
  const int srow = lane >> 3;
  const int scol = ((lane & 7) * 8) ^ ((lane & 32) >> 1);     // stage swizzle

  auto stgA = [&](int q, int h, int t) {
#pragma unroll
    for (int j = 0; j < SWA; ++j) {
      const ushort_t* g = Ab + (long long)(h * (BM / 2) + wid * (8 * SWA) + j * 8 + srow) * lda
                             + t * 64 + scol;
      __builtin_amdgcn_global_load_lds(
          (const __attribute__((address_space(1))) void*)g,
          (__attribute__((address_space(3))) void*)
            (&lds_[q * BUF + h * AH + (wid * (64 * SWA) + j * 64) * 8]),
          16, 0, 0);
    }
  };
  auto stgB = [&](int q, int h, int t) {
#pragma unroll
    for (int j = 0; j < 2; ++j) {
      const ushort_t* g = Bb + (long long)(h * 128 + wid * 16 + j * 8 + srow) * ldb
                             + t * 64 + scol;
      __builtin_amdgcn_global_load_lds(
          (const __attribute__((address_space(1))) void*)g,
          (__attribute__((address_space(3))) void*)
            (&lds_[q * BUF + 2 * AH + h * BH + (wid * 128 + j * 64) * 8]),
          16, 0, 0);
    }
  };

  f32x4 acc[MF][4];
#pragma unroll
  for (int m = 0; m < MF; ++m)
#pragma unroll
    for (int n = 0; n < 4; ++n)
#pragma unroll
      for (int j = 0; j < 4; ++j) acc[m][n][j] = 0.f;

  // prologue: tile0 (A,B) + tile1 A
  stgA(0, 0, 0); stgA(0, 1, 0);
  stgB(0, 0, 0); stgB(0, 1, 0);
  stgA(1, 0, 1); stgA(1, 1, 1);
  if constexpr (SWA == 2) asm volatile("s_waitcnt vmcnt(4)" ::: "memory");
  else                    asm volatile("s_waitcnt vmcnt(2)" ::: "memory");
  __builtin_amdgcn_s_barrier();

  const int NT = K >> 6;
  bf16x8 af[MH], bf[4];

  for (int t = 0; t < NT; ++t) {
    const int q = t & 1;
    const ushort_t* Al = &lds_[q * BUF + wr * AH];
    const ushort_t* Bl = &lds_[q * BUF + 2 * AH + (wc >> 1) * BH + (wc & 1) * 4096];

    // ---- phase 1: kslice 0, m-half 0 (+ all 4 B frags @k0)
#pragma unroll
    for (int n = 0; n < 4; ++n) bf[n] = *(const bf16x8*)(Bl + (n * 16 + l15) * 64 + kx);
#pragma unroll
    for (int m = 0; m < MH; ++m) af[m] = *(const bf16x8*)(Al + (m * 16 + l15) * 64 + kx);
    if (t + 1 < NT) stgB(q ^ 1, 0, t + 1);
    __builtin_amdgcn_s_barrier();
    __builtin_amdgcn_s_setprio(1);
#pragma unroll
    for (int m = 0; m < MH; ++m)
#pragma unroll
      for (int n = 0; n < 4; ++n)
        acc[m][n] = __builtin_amdgcn_mfma_f32_16x16x32_bf16(af[m], bf[n], acc[m][n], 0, 0, 0);
    __builtin_amdgcn_s_setprio(0);
    __builtin_amdgcn_s_barrier();

    // ---- phase 2: kslice 0, m-half 1 (B frags reused)
#pragma unroll
    for (int m = 0; m < MH; ++m) af[m] = *(const bf16x8*)(Al + ((MH + m) * 16 + l15) * 64 + kx);
    if (t + 1 < NT) stgB(q ^ 1, 1, t + 1);
    __builtin_amdgcn_s_barrier();
    __builtin_amdgcn_s_setprio(1);
#pragma unroll
    for (int m = 0; m < MH; ++m)
#pragma unroll
      for (int n = 0; n < 4; ++n)
        acc[MH + m][n] = __builtin_amdgcn_mfma_f32_16x16x32_bf16(af[m], bf[n], acc[MH + m][n], 0, 0, 0);
    __builtin_amdgcn_s_setprio(0);
    __builtin_amdgcn_s_barrier();

    // ---- phase 3: kslice 1, m-half 0
#pragma unroll
    for (int n = 0; n < 4; ++n) bf[n] = *(const bf16x8*)(Bl + (n * 16 + l15) * 64 + 32 + kx);
#pragma unroll
    for (int m = 0; m < MH; ++m) af[m] = *(const bf16x8*)(Al + (m * 16 + l15) * 64 + 32 + kx);
    __builtin_amdgcn_s_barrier();
    __builtin_amdgcn_s_setprio(1);
#pragma unroll
    for (int m = 0; m < MH; ++m)
#pragma unroll
      for (int n = 0; n < 4; ++n)
        acc[m][n] = __builtin_amdgcn_mfma_f32_16x16x32_bf16(af[m], bf[n], acc[m][n], 0, 0, 0);
    __builtin_amdgcn_s_setprio(0);
    __builtin_amdgcn_s_barrier();

    // ---- phase 4: kslice 1, m-half 1; stage A(t+2) after all A-reads issued
#pragma unroll
    for (int m = 0; m < MH; ++m) af[m] = *(const bf16x8*)(Al + ((MH + m) * 16 + l15) * 64 + 32 + kx);
    if (t + 2 < NT) { stgA(q, 0, t + 2); stgA(q, 1, t + 2); }
    __builtin_amdgcn_s_barrier();
    __builtin_amdgcn_s_setprio(1);
#pragma unroll
    for (int m = 0; m < MH; ++m)
#pragma unroll
      for (int n = 0; n < 4; ++n)
        acc[MH + m][n] = __builtin_amdgcn_mfma_f32_16x16x32_bf16(af[m], bf[n], acc[MH + m][n], 0, 0, 0);
    __builtin_amdgcn_s_setprio(0);
    if (t < NT - 2) {
      if constexpr (SWA == 2) asm volatile("s_waitcnt vmcnt(4)" ::: "memory");
      else                    asm volatile("s_waitcnt vmcnt(2)" ::: "memory");
    } else if (t == NT - 2) {
      asm volatile("s_waitcnt vmcnt(0)" ::: "memory");
    }
    __builtin_amdgcn_s_barrier();
  }

  // epilogue: C/D layout col=lane&15, row=(lane>>4)*4+j
  const int r4 = (lane >> 4) * 4;
  const long long crow0 = (long long)by * BM + wr * (BM / 2);
  const int ccol0 = bx * 256 + wc * 64;
#pragma unroll
  for (int n = 0; n < 4; ++n) {
    const int cg = ccol0 + n * 16 + l15;
    const float badd = bias ? bias[cg] : 0.f;
    ushort_t* outp = (ushort_t*)C0;
    int col = cg;
    if constexpr (MODE == 2) {
      const int sel = cg >> 10;
      col = cg & 1023;
      outp = (ushort_t*)(sel == 0 ? C0 : (sel == 1 ? C1 : C2));
    }
#pragma unroll
    for (int m = 0; m < MF; ++m)
#pragma unroll
      for (int j = 0; j < 4; ++j) {
        const long long rg = crow0 + m * 16 + r4 + j;
        const float v = acc[m][n][j] * scale + badd;
        if constexpr (MODE == 0)
          ((float*)C0)[(long long)z * sCz + rg * ldc + cg] = v;
        else if constexpr (MODE == 1)
          ((ushort_t*)C0)[(long long)z * sCz + rg * ldc + cg] = f2bf(v);
        else
          outp[rg * 1024 + col] = f2bf(v);
      }
  }
}

// ---------------------------------------------------------------------------
__global__ __launch_bounds__(256)
void cast_f32_bf16(const float* __restrict__ in, ushort_t* __restrict__ out, long long n)
{
  long long i = ((long long)blockIdx.x * blockDim.x + threadIdx.x) * 4;
  const long long stride = (long long)gridDim.x * blockDim.x * 4;
  for (; i < n; i += stride) {
    const float4 v = *(const float4*)&in[i];
    ushort4 o;
    o.x = f2bf(v.x); o.y = f2bf(v.y); o.z = f2bf(v.z); o.w = f2bf(v.w);
    *(ushort4*)&out[i] = o;
  }
}

// cast 3 weight matrices into concatenated w3 [3072][1024] + bias concat [3072]
__global__ __launch_bounds__(256)
void prep_w(const float* __restrict__ Wq, const float* __restrict__ Wk,
            const float* __restrict__ Wv, const float* __restrict__ bq,
            const float* __restrict__ bk, const float* __restrict__ bv,
            ushort_t* __restrict__ w3, float* __restrict__ bcat)
{
  const int which = blockIdx.x >> 10;
  const float* W = (which == 0) ? Wq : (which == 1) ? Wk : Wv;
  const long long i = ((long long)(blockIdx.x & 1023) * 256 + threadIdx.x) * 4;
  const float4 v = *(const float4*)&W[i];
  ushort4 o;
  o.x = f2bf(v.x); o.y = f2bf(v.y); o.z = f2bf(v.z); o.w = f2bf(v.w);
  *(ushort4*)&w3[(long long)which * 1024 * 1024 + i] = o;
  const int g = blockIdx.x * 256 + threadIdx.x;
  if (g < 3072) bcat[g] = (g < 1024) ? bq[g] : (g < 2048) ? bk[g - 1024] : bv[g - 2048];
}

// bf16 transpose per batch: in[z][rows][ldIn] -> out[z][cols][rows]
__global__ __launch_bounds__(256)
void transpose_bf16(const ushort_t* __restrict__ in, ushort_t* __restrict__ out,
                    int rows, int cols, int ldIn, long long sIn, long long sOut)
{
  __shared__ ushort_t t[64][65];
  in  += (long long)blockIdx.z * sIn;
  out += (long long)blockIdx.z * sOut;
  const int r0 = blockIdx.y * 64;
  const int c0 = blockIdx.x * 64;
  const int tx = threadIdx.x & 15, ty = threadIdx.x >> 4;
#pragma unroll
  for (int r = 0; r < 4; ++r) {
    const ushort4 v = *(const ushort4*)&in[(long long)(r0 + ty * 4 + r) * ldIn + c0 + tx * 4];
    t[ty * 4 + r][tx * 4 + 0] = v.x;
    t[ty * 4 + r][tx * 4 + 1] = v.y;
    t[ty * 4 + r][tx * 4 + 2] = v.z;
    t[ty * 4 + r][tx * 4 + 3] = v.w;
  }
  __syncthreads();
#pragma unroll
  for (int r = 0; r < 4; ++r) {
    const int d = ty * 4 + r;
    ushort4 v;
    v.x = t[tx * 4 + 0][d];
    v.y = t[tx * 4 + 1][d];
    v.z = t[tx * 4 + 2][d];
    v.w = t[tx * 4 + 3][d];
    *(ushort4*)&out[(long long)(c0 + d) * rows + r0 + tx * 4] = v;
  }
}

// row softmax over 2048 fp32 -> bf16, one block per row
__global__ __launch_bounds__(256)
void softmax2048(const float* __restrict__ Sc, ushort_t* __restrict__ P)
{
  const long long row = blockIdx.x;
  const float* s = Sc + row * 2048;
  const int tid = threadIdx.x;
  const int wave = tid >> 6, lane = tid & 63;

  const float4 a = *(const float4*)&s[tid * 4];
  const float4 b = *(const float4*)&s[1024 + tid * 4];
  float m = fmaxf(fmaxf(fmaxf(a.x, a.y), fmaxf(a.z, a.w)),
                  fmaxf(fmaxf(b.x, b.y), fmaxf(b.z, b.w)));
#pragma unroll
  for (int off = 32; off > 0; off >>= 1) m = fmaxf(m, __shfl_xor(m, off));
  __shared__ float redm[4], reds[4];
  if (lane == 0) redm[wave] = m;
  __syncthreads();
  m = fmaxf(fmaxf(redm[0], redm[1]), fmaxf(redm[2], redm[3]));

  float e[8];
  e[0] = __expf(a.x - m); e[1] = __expf(a.y - m); e[2] = __expf(a.z - m); e[3] = __expf(a.w - m);
  e[4] = __expf(b.x - m); e[5] = __expf(b.y - m); e[6] = __expf(b.z - m); e[7] = __expf(b.w - m);
  float sum = ((e[0] + e[1]) + (e[2] + e[3])) + ((e[4] + e[5]) + (e[6] + e[7]));
#pragma unroll
  for (int off = 32; off > 0; off >>= 1) sum += __shfl_xor(sum, off);
  if (lane == 0) reds[wave] = sum;
  __syncthreads();
  sum = (reds[0] + reds[1]) + (reds[2] + reds[3]);
  const float inv = 1.0f / sum;

  ushort4 o;
  o.x = f2bf(e[0] * inv); o.y = f2bf(e[1] * inv); o.z = f2bf(e[2] * inv); o.w = f2bf(e[3] * inv);
  *(ushort4*)&P[row * 2048 + tid * 4] = o;
  o.x = f2bf(e[4] * inv); o.y = f2bf(e[5] * inv); o.z = f2bf(e[6] * inv); o.w = f2bf(e[7] * inv);
  *(ushort4*)&P[row * 2048 + 1024 + tid * 4] = o;
}

// ---------------------------------------------------------------------------
extern "C" void kernel_launch(void* const* d_in, const int* in_sizes, int n_in,
                              void* d_out, int out_size, void* d_ws, size_t ws_size,
                              hipStream_t stream)
{
  constexpr int B = 4, S = 2048, D = 1024;
  constexpr long long MT = (long long)B * S;        // 8192 tokens
  constexpr long long SD = (long long)S * D;
  constexpr long long SS = (long long)S * S;

  const float* x  = (const float*)d_in[0];
  const float* Wq = (const float*)d_in[1];
  const float* bq = (const float*)d_in[2];
  const float* Wk = (const float*)d_in[3];
  const float* bk = (const float*)d_in[4];
  const float* Wv = (const float*)d_in[5];
  const float* bv = (const float*)d_in[6];
  float* out = (float*)d_out;

  // ws layout (bytes), total 167772160; xb/w3/bcat overlap scores (dead after proj)
  char* base = (char*)d_ws;
  ushort_t* q      = (ushort_t*)(base);               // 16777216
  ushort_t* k      = (ushort_t*)(base + 16777216);    // 16777216
  ushort_t* vt     = (ushort_t*)(base + 33554432);    // 16777216  [4][1024][2048]
  float*    scores = (float*)   (base + 50331648);    // 67108864
  ushort_t* P      = (ushort_t*)(base + 117440512);   // 33554432
  ushort_t* vplain = (ushort_t*)(base + 150994944);   // 16777216  [4][2048][1024]
  ushort_t* xb     = (ushort_t*)(base + 50331648);    // 16777216 (dead after proj)
  ushort_t* w3     = (ushort_t*)(base + 67108864);    // 6291456  (dead after proj)
  float*    bcat   = (float*)   (base + 73400320);    // 12288    (dead after proj)

  // 1) casts
  cast_f32_bf16<<<2048, 256, 0, stream>>>(x, xb, MT * D);
  prep_w<<<3072, 256, 0, stream>>>(Wq, Wk, Wv, bq, bk, bv, w3, bcat);

  // 2) fused QKV projection -> split q / k / vplain (contiguous, ld=1024)
  gemm8p<128, 2><<<dim3(12, 64, 1), 512, 0, stream>>>(
      xb, 0, D, w3, 0, D, q, k, vplain, 0, 1024, D, 1.f, bcat);

  // 3) v -> v^T per batch: [2048][1024] -> [1024][2048]
  transpose_bf16<<<dim3(16, 32, 4), 256, 0, stream>>>(
      vplain, vt, S, D, 1024, SD, SD);

  // 4) QK^T: scores[z] = (q @ k^T) / 32
  gemm8p<256, 0><<<dim3(8, 8, 4), 512, 0, stream>>>(
      q, SD, D, k, SD, D, scores, nullptr, nullptr, SS, S, D, 0.03125f, nullptr);

  // 5) softmax rows
  softmax2048<<<MT, 256, 0, stream>>>(scores, P);

  // 6) PV: out[z] = P @ vt^T
  gemm8p<128, 0><<<dim3(4, 16, 4), 512, 0, stream>>>(
      P, SS, S, vt, (long long)D * S, S, out, nullptr, nullptr, SD, D, S, 1.f, nullptr);
}

// Round 4
// 186.169 us; speedup vs baseline: 1.2986x; 1.0435x over previous
//
#include <hip/hip_runtime.h>

// Attention_13632226198096: B=4, S=2048, D=1024 fp32 single-head attention.
// Round 4: fix 16-bank LDS aliasing (full row&7 XOR swizzle, both-sides),
// per-GEMM XCD rect shapes (proj 4x8, QK 4x2, PV 2x4). 8-phase bf16 MFMA.

typedef unsigned short ushort_t;
typedef __bf16 bf16x8 __attribute__((ext_vector_type(8)));
typedef float f32x4 __attribute__((ext_vector_type(4)));

__device__ __forceinline__ unsigned short f2bf(float f) {
  unsigned u = __builtin_bit_cast(unsigned, f);
  u += 0x7fffu + ((u >> 16) & 1u);
  return (unsigned short)(u >> 16);
}

// ---------------------------------------------------------------------------
// C = scale*(A @ B^T) + bias[col]; A[M,K] lda, B[N,K] ldb. BN=256, BK=64.
// 512 thr = 8 waves (2M x 4N); per-wave out (BM/2) x 64.
// LDS swizzle: elem stored at row*64 + (k ^ ((row&7)<<3)) -> all 32 banks per
// ds_read_b128 wavefront (8 words/bank). Stage: linear LDS dest (lane*16B),
// pre-swizzled global col = 8*((lane&7)^((lane>>3)&7)).
// XCD swizzle: RX x RY block rects, rect-per-XCD-per-round (T1, bijective).
// MODE 0: fp32 C0; 1: bf16 C0; 2: qkv column-split bf16 (C0/C1/C2, ldc 1024).
// ---------------------------------------------------------------------------
template<int BM, int MODE, int RX, int RY>
__global__ __launch_bounds__(512, 1)
void gemm8p(const ushort_t* __restrict__ A, long long sAz, int lda,
            const ushort_t* __restrict__ Bm, long long sBz, int ldb,
            void* __restrict__ C0, void* __restrict__ C1, void* __restrict__ C2,
            long long sCz, int ldc, int K, float scale, const float* __restrict__ bias)
{
  constexpr int MF  = BM / 32;        // m-frags per wave (8 or 4)
  constexpr int MH  = MF / 2;         // per phase
  constexpr int AH  = (BM / 2) * 64;  // elems per A half-slot
  constexpr int BH  = 128 * 64;
  constexpr int BUF = 2 * AH + 2 * BH;
  constexpr int SWA = AH / 4096;      // global_load_lds per wave per A-half (1|2)
  constexpr int BPR = RX * RY;        // blocks per XCD rect
  __shared__ ushort_t lds_[2 * BUF] __attribute__((aligned(16)));

  // XCD-aware bijective rect swizzle
  const int gx = gridDim.x;
  const int lin = blockIdx.y * gx + blockIdx.x;
  const int xcd = lin & 7, s = lin >> 3;
  const int chunk = s / BPR, idx = s % BPR;
  const int rect = chunk * 8 + xcd;
  const int nrx = gx / RX;
  const int bx = (rect % nrx) * RX + (idx % RX);
  const int by = (rect / nrx) * RY + (idx / RX);

  const int z = blockIdx.z;
  const ushort_t* Ab = A  + (long long)z * sAz + (long long)by * BM  * lda;
  const ushort_t* Bb = Bm + (long long)z * sBz + (long long)bx * 256 * ldb;

  const int tid = threadIdx.x, wid = tid >> 6, lane = tid & 63;
  const int wr = wid >> 2, wc = wid & 3;
  const int l15 = lane & 15;
  // read k-offsets (elems) for kslice 0 / 1: 8*((g+4ks) ^ (row&7))
  const int kx0 = (((lane >> 4) + 0) ^ (l15 & 7)) * 8;
  const int kx1 = (((lane >> 4) + 4) ^ (l15 & 7)) * 8;
  // stage: global source col pre-swizzled so linear LDS write lands swizzled
  const int srow = lane >> 3;
  const int scol = ((lane & 7) ^ (srow & 7)) * 8;

  auto stgA = [&](int q, int h, int t) {
#pragma unroll
    for (int j = 0; j < SWA; ++j) {
      const ushort_t* g = Ab + (long long)(h * (BM / 2) + wid * (8 * SWA) + j * 8 + srow) * lda
                             + t * 64 + scol;
      __builtin_amdgcn_global_load_lds(
          (const __attribute__((address_space(1))) void*)g,
          (__attribute__((address_space(3))) void*)
            (&lds_[q * BUF + h * AH + (wid * (64 * SWA) + j * 64) * 8]),
          16, 0, 0);
    }
  };
  auto stgB = [&](int q, int h, int t) {
#pragma unroll
    for (int j = 0; j < 2; ++j) {
      const ushort_t* g = Bb + (long long)(h * 128 + wid * 16 + j * 8 + srow) * ldb
                             + t * 64 + scol;
      __builtin_amdgcn_global_load_lds(
          (const __attribute__((address_space(1))) void*)g,
          (__attribute__((address_space(3))) void*)
            (&lds_[q * BUF + 2 * AH + h * BH + (wid * 128 + j * 64) * 8]),
          16, 0, 0);
    }
  };

  f32x4 acc[MF][4];
#pragma unroll
  for (int m = 0; m < MF; ++m)
#pragma unroll
    for (int n = 0; n < 4; ++n)
#pragma unroll
      for (int j = 0; j < 4; ++j) acc[m][n][j] = 0.f;

  // prologue: tile0 (A,B) + tile1 A
  stgA(0, 0, 0); stgA(0, 1, 0);
  stgB(0, 0, 0); stgB(0, 1, 0);
  stgA(1, 0, 1); stgA(1, 1, 1);
  if constexpr (SWA == 2) asm volatile("s_waitcnt vmcnt(4)" ::: "memory");
  else                    asm volatile("s_waitcnt vmcnt(2)" ::: "memory");
  __builtin_amdgcn_s_barrier();

  const int NT = K >> 6;
  bf16x8 af[MH], bf[4];

  for (int t = 0; t < NT; ++t) {
    const int q = t & 1;
    const ushort_t* Al = &lds_[q * BUF + wr * AH];
    const ushort_t* Bl = &lds_[q * BUF + 2 * AH + (wc >> 1) * BH + (wc & 1) * 4096];

    // ---- phase 1: kslice 0, m-half 0 (+ all 4 B frags @k0)
#pragma unroll
    for (int n = 0; n < 4; ++n) bf[n] = *(const bf16x8*)(Bl + (n * 16 + l15) * 64 + kx0);
#pragma unroll
    for (int m = 0; m < MH; ++m) af[m] = *(const bf16x8*)(Al + (m * 16 + l15) * 64 + kx0);
    if (t + 1 < NT) stgB(q ^ 1, 0, t + 1);
    __builtin_amdgcn_s_barrier();
    __builtin_amdgcn_s_setprio(1);
#pragma unroll
    for (int m = 0; m < MH; ++m)
#pragma unroll
      for (int n = 0; n < 4; ++n)
        acc[m][n] = __builtin_amdgcn_mfma_f32_16x16x32_bf16(af[m], bf[n], acc[m][n], 0, 0, 0);
    __builtin_amdgcn_s_setprio(0);
    __builtin_amdgcn_s_barrier();

    // ---- phase 2: kslice 0, m-half 1 (B frags reused)
#pragma unroll
    for (int m = 0; m < MH; ++m) af[m] = *(const bf16x8*)(Al + ((MH + m) * 16 + l15) * 64 + kx0);
    if (t + 1 < NT) stgB(q ^ 1, 1, t + 1);
    __builtin_amdgcn_s_barrier();
    __builtin_amdgcn_s_setprio(1);
#pragma unroll
    for (int m = 0; m < MH; ++m)
#pragma unroll
      for (int n = 0; n < 4; ++n)
        acc[MH + m][n] = __builtin_amdgcn_mfma_f32_16x16x32_bf16(af[m], bf[n], acc[MH + m][n], 0, 0, 0);
    __builtin_amdgcn_s_setprio(0);
    __builtin_amdgcn_s_barrier();

    // ---- phase 3: kslice 1, m-half 0
#pragma unroll
    for (int n = 0; n < 4; ++n) bf[n] = *(const bf16x8*)(Bl + (n * 16 + l15) * 64 + kx1);
#pragma unroll
    for (int m = 0; m < MH; ++m) af[m] = *(const bf16x8*)(Al + (m * 16 + l15) * 64 + kx1);
    __builtin_amdgcn_s_barrier();
    __builtin_amdgcn_s_setprio(1);
#pragma unroll
    for (int m = 0; m < MH; ++m)
#pragma unroll
      for (int n = 0; n < 4; ++n)
        acc[m][n] = __builtin_amdgcn_mfma_f32_16x16x32_bf16(af[m], bf[n], acc[m][n], 0, 0, 0);
    __builtin_amdgcn_s_setprio(0);
    __builtin_amdgcn_s_barrier();

    // ---- phase 4: kslice 1, m-half 1; stage A(t+2) after all A-reads issued
#pragma unroll
    for (int m = 0; m < MH; ++m) af[m] = *(const bf16x8*)(Al + ((MH + m) * 16 + l15) * 64 + kx1);
    if (t + 2 < NT) { stgA(q, 0, t + 2); stgA(q, 1, t + 2); }
    __builtin_amdgcn_s_barrier();
    __builtin_amdgcn_s_setprio(1);
#pragma unroll
    for (int m = 0; m < MH; ++m)
#pragma unroll
      for (int n = 0; n < 4; ++n)
        acc[MH + m][n] = __builtin_amdgcn_mfma_f32_16x16x32_bf16(af[m], bf[n], acc[MH + m][n], 0, 0, 0);
    __builtin_amdgcn_s_setprio(0);
    if (t < NT - 2) {
      if constexpr (SWA == 2) asm volatile("s_waitcnt vmcnt(4)" ::: "memory");
      else                    asm volatile("s_waitcnt vmcnt(2)" ::: "memory");
    } else if (t == NT - 2) {
      asm volatile("s_waitcnt vmcnt(0)" ::: "memory");
    }
    __builtin_amdgcn_s_barrier();
  }

  // epilogue: C/D layout col=lane&15, row=(lane>>4)*4+j
  const int r4 = (lane >> 4) * 4;
  const long long crow0 = (long long)by * BM + wr * (BM / 2);
  const int ccol0 = bx * 256 + wc * 64;
#pragma unroll
  for (int n = 0; n < 4; ++n) {
    const int cg = ccol0 + n * 16 + l15;
    const float badd = bias ? bias[cg] : 0.f;
    ushort_t* outp = (ushort_t*)C0;
    int col = cg;
    if constexpr (MODE == 2) {
      const int sel = cg >> 10;
      col = cg & 1023;
      outp = (ushort_t*)(sel == 0 ? C0 : (sel == 1 ? C1 : C2));
    }
#pragma unroll
    for (int m = 0; m < MF; ++m)
#pragma unroll
      for (int j = 0; j < 4; ++j) {
        const long long rg = crow0 + m * 16 + r4 + j;
        const float v = acc[m][n][j] * scale + badd;
        if constexpr (MODE == 0)
          ((float*)C0)[(long long)z * sCz + rg * ldc + cg] = v;
        else if constexpr (MODE == 1)
          ((ushort_t*)C0)[(long long)z * sCz + rg * ldc + cg] = f2bf(v);
        else
          outp[rg * 1024 + col] = f2bf(v);
      }
  }
}

// ---------------------------------------------------------------------------
__global__ __launch_bounds__(256)
void cast_f32_bf16(const float* __restrict__ in, ushort_t* __restrict__ out, long long n)
{
  long long i = ((long long)blockIdx.x * blockDim.x + threadIdx.x) * 4;
  const long long stride = (long long)gridDim.x * blockDim.x * 4;
  for (; i < n; i += stride) {
    const float4 v = *(const float4*)&in[i];
    ushort4 o;
    o.x = f2bf(v.x); o.y = f2bf(v.y); o.z = f2bf(v.z); o.w = f2bf(v.w);
    *(ushort4*)&out[i] = o;
  }
}

// cast 3 weight matrices into concatenated w3 [3072][1024] + bias concat [3072]
__global__ __launch_bounds__(256)
void prep_w(const float* __restrict__ Wq, const float* __restrict__ Wk,
            const float* __restrict__ Wv, const float* __restrict__ bq,
            const float* __restrict__ bk, const float* __restrict__ bv,
            ushort_t* __restrict__ w3, float* __restrict__ bcat)
{
  const int which = blockIdx.x >> 10;
  const float* W = (which == 0) ? Wq : (which == 1) ? Wk : Wv;
  const long long i = ((long long)(blockIdx.x & 1023) * 256 + threadIdx.x) * 4;
  const float4 v = *(const float4*)&W[i];
  ushort4 o;
  o.x = f2bf(v.x); o.y = f2bf(v.y); o.z = f2bf(v.z); o.w = f2bf(v.w);
  *(ushort4*)&w3[(long long)which * 1024 * 1024 + i] = o;
  const int g = blockIdx.x * 256 + threadIdx.x;
  if (g < 3072) bcat[g] = (g < 1024) ? bq[g] : (g < 2048) ? bk[g - 1024] : bv[g - 2048];
}

// bf16 transpose per batch: in[z][rows][ldIn] -> out[z][cols][rows]
__global__ __launch_bounds__(256)
void transpose_bf16(const ushort_t* __restrict__ in, ushort_t* __restrict__ out,
                    int rows, int cols, int ldIn, long long sIn, long long sOut)
{
  __shared__ ushort_t t[64][65];
  in  += (long long)blockIdx.z * sIn;
  out += (long long)blockIdx.z * sOut;
  const int r0 = blockIdx.y * 64;
  const int c0 = blockIdx.x * 64;
  const int tx = threadIdx.x & 15, ty = threadIdx.x >> 4;
#pragma unroll
  for (int r = 0; r < 4; ++r) {
    const ushort4 v = *(const ushort4*)&in[(long long)(r0 + ty * 4 + r) * ldIn + c0 + tx * 4];
    t[ty * 4 + r][tx * 4 + 0] = v.x;
    t[ty * 4 + r][tx * 4 + 1] = v.y;
    t[ty * 4 + r][tx * 4 + 2] = v.z;
    t[ty * 4 + r][tx * 4 + 3] = v.w;
  }
  __syncthreads();
#pragma unroll
  for (int r = 0; r < 4; ++r) {
    const int d = ty * 4 + r;
    ushort4 v;
    v.x = t[tx * 4 + 0][d];
    v.y = t[tx * 4 + 1][d];
    v.z = t[tx * 4 + 2][d];
    v.w = t[tx * 4 + 3][d];
    *(ushort4*)&out[(long long)(c0 + d) * rows + r0 + tx * 4] = v;
  }
}

// row softmax over 2048 fp32 -> bf16, one block per row
__global__ __launch_bounds__(256)
void softmax2048(const float* __restrict__ Sc, ushort_t* __restrict__ P)
{
  const long long row = blockIdx.x;
  const float* s = Sc + row * 2048;
  const int tid = threadIdx.x;
  const int wave = tid >> 6, lane = tid & 63;

  const float4 a = *(const float4*)&s[tid * 4];
  const float4 b = *(const float4*)&s[1024 + tid * 4];
  float m = fmaxf(fmaxf(fmaxf(a.x, a.y), fmaxf(a.z, a.w)),
                  fmaxf(fmaxf(b.x, b.y), fmaxf(b.z, b.w)));
#pragma unroll
  for (int off = 32; off > 0; off >>= 1) m = fmaxf(m, __shfl_xor(m, off));
  __shared__ float redm[4], reds[4];
  if (lane == 0) redm[wave] = m;
  __syncthreads();
  m = fmaxf(fmaxf(redm[0], redm[1]), fmaxf(redm[2], redm[3]));

  float e[8];
  e[0] = __expf(a.x - m); e[1] = __expf(a.y - m); e[2] = __expf(a.z - m); e[3] = __expf(a.w - m);
  e[4] = __expf(b.x - m); e[5] = __expf(b.y - m); e[6] = __expf(b.z - m); e[7] = __expf(b.w - m);
  float sum = ((e[0] + e[1]) + (e[2] + e[3])) + ((e[4] + e[5]) + (e[6] + e[7]));
#pragma unroll
  for (int off = 32; off > 0; off >>= 1) sum += __shfl_xor(sum, off);
  if (lane == 0) reds[wave] = sum;
  __syncthreads();
  sum = (reds[0] + reds[1]) + (reds[2] + reds[3]);
  const float inv = 1.0f / sum;

  ushort4 o;
  o.x = f2bf(e[0] * inv); o.y = f2bf(e[1] * inv); o.z = f2bf(e[2] * inv); o.w = f2bf(e[3] * inv);
  *(ushort4*)&P[row * 2048 + tid * 4] = o;
  o.x = f2bf(e[4] * inv); o.y = f2bf(e[5] * inv); o.z = f2bf(e[6] * inv); o.w = f2bf(e[7] * inv);
  *(ushort4*)&P[row * 2048 + 1024 + tid * 4] = o;
}

// ---------------------------------------------------------------------------
extern "C" void kernel_launch(void* const* d_in, const int* in_sizes, int n_in,
                              void* d_out, int out_size, void* d_ws, size_t ws_size,
                              hipStream_t stream)
{
  constexpr int B = 4, S = 2048, D = 1024;
  constexpr long long MT = (long long)B * S;        // 8192 tokens
  constexpr long long SD = (long long)S * D;
  constexpr long long SS = (long long)S * S;

  const float* x  = (const float*)d_in[0];
  const float* Wq = (const float*)d_in[1];
  const float* bq = (const float*)d_in[2];
  const float* Wk = (const float*)d_in[3];
  const float* bk = (const float*)d_in[4];
  const float* Wv = (const float*)d_in[5];
  const float* bv = (const float*)d_in[6];
  float* out = (float*)d_out;

  // ws layout (bytes), total 167772160; xb/w3/bcat overlap scores (dead after proj)
  char* base = (char*)d_ws;
  ushort_t* q      = (ushort_t*)(base);               // 16777216
  ushort_t* k      = (ushort_t*)(base + 16777216);    // 16777216
  ushort_t* vt     = (ushort_t*)(base + 33554432);    // 16777216  [4][1024][2048]
  float*    scores = (float*)   (base + 50331648);    // 67108864
  ushort_t* P      = (ushort_t*)(base + 117440512);   // 33554432
  ushort_t* vplain = (ushort_t*)(base + 150994944);   // 16777216  [4][2048][1024]
  ushort_t* xb     = (ushort_t*)(base + 50331648);    // 16777216 (dead after proj)
  ushort_t* w3     = (ushort_t*)(base + 67108864);    // 6291456  (dead after proj)
  float*    bcat   = (float*)   (base + 73400320);    // 12288    (dead after proj)

  // 1) casts
  cast_f32_bf16<<<2048, 256, 0, stream>>>(x, xb, MT * D);
  prep_w<<<3072, 256, 0, stream>>>(Wq, Wk, Wv, bq, bk, bv, w3, bcat);

  // 2) fused QKV projection -> split q / k / vplain (contiguous, ld=1024)
  gemm8p<128, 2, 4, 8><<<dim3(12, 64, 1), 512, 0, stream>>>(
      xb, 0, D, w3, 0, D, q, k, vplain, 0, 1024, D, 1.f, bcat);

  // 3) v -> v^T per batch: [2048][1024] -> [1024][2048]
  transpose_bf16<<<dim3(16, 32, 4), 256, 0, stream>>>(
      vplain, vt, S, D, 1024, SD, SD);

  // 4) QK^T: scores[z] = (q @ k^T) / 32
  gemm8p<256, 0, 4, 2><<<dim3(8, 8, 4), 512, 0, stream>>>(
      q, SD, D, k, SD, D, scores, nullptr, nullptr, SS, S, D, 0.03125f, nullptr);

  // 5) softmax rows
  softmax2048<<<MT, 256, 0, stream>>>(scores, P);

  // 6) PV: out[z] = P @ vt^T
  gemm8p<128, 0, 2, 4><<<dim3(4, 16, 4), 512, 0, stream>>>(
      P, SS, S, vt, (long long)D * S, S, out, nullptr, nullptr, SD, D, S, 1.f, nullptr);
}

// Round 5
// 185.047 us; speedup vs baseline: 1.3065x; 1.0061x over previous
//
#include <hip/hip_runtime.h>

// Attention_13632226198096: B=4, S=2048, D=1024 fp32 single-head attention.
// Round 5: BM=128 GEMMs (proj, PV) restructured to 2 phases/K-tile
// (16 MFMA/phase, 4 barriers/tile) to match m201 compute density.
// BM=256 (QK) keeps 4-phase. Conflict-free row&7 XOR LDS swizzle (r4),
// per-GEMM XCD rects (r3/r4).

typedef unsigned short ushort_t;
typedef __bf16 bf16x8 __attribute__((ext_vector_type(8)));
typedef float f32x4 __attribute__((ext_vector_type(4)));

__device__ __forceinline__ unsigned short f2bf(float f) {
  unsigned u = __builtin_bit_cast(unsigned, f);
  u += 0x7fffu + ((u >> 16) & 1u);
  return (unsigned short)(u >> 16);
}

// ---------------------------------------------------------------------------
// C = scale*(A @ B^T) + bias[col]; A[M,K] lda, B[N,K] ldb. BN=256, BK=64.
// 512 thr = 8 waves (2M x 4N); per-wave out (BM/2) x 64.
// LDS swizzle: elem at row*64 + (k ^ ((row&7)<<3)); stage via pre-swizzled
// global col; reads conflict-free across all 32 banks.
// BM=128: 2 phases/tile (ph1: all A + B-k0, 16 MFMA; ph2: B-k1, 16 MFMA).
// BM=256: 4 phases/tile (16 MFMA each).
// MODE 0: fp32 C0; 1: bf16 C0; 2: qkv column-split bf16 (C0/C1/C2, ldc 1024).
// ---------------------------------------------------------------------------
template<int BM, int MODE, int RX, int RY>
__global__ __launch_bounds__(512, 1)
void gemm8p(const ushort_t* __restrict__ A, long long sAz, int lda,
            const ushort_t* __restrict__ Bm, long long sBz, int ldb,
            void* __restrict__ C0, void* __restrict__ C1, void* __restrict__ C2,
            long long sCz, int ldc, int K, float scale, const float* __restrict__ bias)
{
  constexpr int MF  = BM / 32;        // m-frags per wave (8 or 4)
  constexpr int MH  = MF / 2;
  constexpr int AH  = (BM / 2) * 64;  // elems per A half-slot
  constexpr int BH  = 128 * 64;
  constexpr int BUF = 2 * AH + 2 * BH;
  constexpr int SWA = AH / 4096;      // gloads per wave per A-half (1|2)
  constexpr int BPR = RX * RY;
  __shared__ ushort_t lds_[2 * BUF] __attribute__((aligned(16)));

  // XCD-aware bijective rect swizzle
  const int gx = gridDim.x;
  const int lin = blockIdx.y * gx + blockIdx.x;
  const int xcd = lin & 7, s = lin >> 3;
  const int chunk = s / BPR, idx = s % BPR;
  const int rect = chunk * 8 + xcd;
  const int nrx = gx / RX;
  const int bx = (rect % nrx) * RX + (idx % RX);
  const int by = (rect / nrx) * RY + (idx / RX);

  const int z = blockIdx.z;
  const ushort_t* Ab = A  + (long long)z * sAz + (long long)by * BM  * lda;
  const ushort_t* Bb = Bm + (long long)z * sBz + (long long)bx * 256 * ldb;

  const int tid = threadIdx.x, wid = tid >> 6, lane = tid & 63;
  const int wr = wid >> 2, wc = wid & 3;
  const int l15 = lane & 15;
  const int kx0 = (((lane >> 4) + 0) ^ (l15 & 7)) * 8;
  const int kx1 = (((lane >> 4) + 4) ^ (l15 & 7)) * 8;
  const int srow = lane >> 3;
  const int scol = ((lane & 7) ^ (srow & 7)) * 8;

  auto stgA = [&](int q, int h, int t) {
#pragma unroll
    for (int j = 0; j < SWA; ++j) {
      const ushort_t* g = Ab + (long long)(h * (BM / 2) + wid * (8 * SWA) + j * 8 + srow) * lda
                             + t * 64 + scol;
      __builtin_amdgcn_global_load_lds(
          (const __attribute__((address_space(1))) void*)g,
          (__attribute__((address_space(3))) void*)
            (&lds_[q * BUF + h * AH + (wid * (64 * SWA) + j * 64) * 8]),
          16, 0, 0);
    }
  };
  auto stgB = [&](int q, int h, int t) {
#pragma unroll
    for (int j = 0; j < 2; ++j) {
      const ushort_t* g = Bb + (long long)(h * 128 + wid * 16 + j * 8 + srow) * ldb
                             + t * 64 + scol;
      __builtin_amdgcn_global_load_lds(
          (const __attribute__((address_space(1))) void*)g,
          (__attribute__((address_space(3))) void*)
            (&lds_[q * BUF + 2 * AH + h * BH + (wid * 128 + j * 64) * 8]),
          16, 0, 0);
    }
  };

  f32x4 acc[MF][4];
#pragma unroll
  for (int m = 0; m < MF; ++m)
#pragma unroll
    for (int n = 0; n < 4; ++n)
#pragma unroll
      for (int j = 0; j < 4; ++j) acc[m][n][j] = 0.f;

  // prologue: tile0 (A,B) + tile1 A
  stgA(0, 0, 0); stgA(0, 1, 0);
  stgB(0, 0, 0); stgB(0, 1, 0);
  stgA(1, 0, 1); stgA(1, 1, 1);
  if constexpr (SWA == 2) asm volatile("s_waitcnt vmcnt(4)" ::: "memory");
  else                    asm volatile("s_waitcnt vmcnt(2)" ::: "memory");
  __builtin_amdgcn_s_barrier();

  const int NT = K >> 6;

  if constexpr (MF == 4) {
    // ---------------- 2-phase schedule (BM=128) ----------------
    bf16x8 a0[4], a1[4], bf[4];
    for (int t = 0; t < NT; ++t) {
      const int q = t & 1;
      const ushort_t* Al = &lds_[q * BUF + wr * AH];
      const ushort_t* Bl = &lds_[q * BUF + 2 * AH + (wc >> 1) * BH + (wc & 1) * 4096];

      // ph1: all A frags (k0+k1) + B k0; stage B(t+1)
#pragma unroll
      for (int m = 0; m < 4; ++m) a0[m] = *(const bf16x8*)(Al + (m * 16 + l15) * 64 + kx0);
#pragma unroll
      for (int n = 0; n < 4; ++n) bf[n] = *(const bf16x8*)(Bl + (n * 16 + l15) * 64 + kx0);
#pragma unroll
      for (int m = 0; m < 4; ++m) a1[m] = *(const bf16x8*)(Al + (m * 16 + l15) * 64 + kx1);
      __builtin_amdgcn_sched_barrier(0);
      if (t + 1 < NT) { stgB(q ^ 1, 0, t + 1); stgB(q ^ 1, 1, t + 1); }
      __builtin_amdgcn_s_barrier();
      __builtin_amdgcn_s_setprio(1);
#pragma unroll
      for (int m = 0; m < 4; ++m)
#pragma unroll
        for (int n = 0; n < 4; ++n)
          acc[m][n] = __builtin_amdgcn_mfma_f32_16x16x32_bf16(a0[m], bf[n], acc[m][n], 0, 0, 0);
      __builtin_amdgcn_s_setprio(0);
      __builtin_amdgcn_s_barrier();

      // ph2: B k1; stage A(t+2)
#pragma unroll
      for (int n = 0; n < 4; ++n) bf[n] = *(const bf16x8*)(Bl + (n * 16 + l15) * 64 + kx1);
      __builtin_amdgcn_sched_barrier(0);
      if (t + 2 < NT) { stgA(q, 0, t + 2); stgA(q, 1, t + 2); }
      __builtin_amdgcn_s_barrier();
      __builtin_amdgcn_s_setprio(1);
#pragma unroll
      for (int m = 0; m < 4; ++m)
#pragma unroll
        for (int n = 0; n < 4; ++n)
          acc[m][n] = __builtin_amdgcn_mfma_f32_16x16x32_bf16(a1[m], bf[n], acc[m][n], 0, 0, 0);
      __builtin_amdgcn_s_setprio(0);
      if (t < NT - 2)       asm volatile("s_waitcnt vmcnt(2)" ::: "memory");
      else if (t == NT - 2) asm volatile("s_waitcnt vmcnt(0)" ::: "memory");
      __builtin_amdgcn_s_barrier();
    }
  } else {
    // ---------------- 4-phase schedule (BM=256) ----------------
    bf16x8 af[MH], bf[4];
    for (int t = 0; t < NT; ++t) {
      const int q = t & 1;
      const ushort_t* Al = &lds_[q * BUF + wr * AH];
      const ushort_t* Bl = &lds_[q * BUF + 2 * AH + (wc >> 1) * BH + (wc & 1) * 4096];

      // ph1: kslice0, m-half 0 + all B@k0
#pragma unroll
      for (int n = 0; n < 4; ++n) bf[n] = *(const bf16x8*)(Bl + (n * 16 + l15) * 64 + kx0);
#pragma unroll
      for (int m = 0; m < MH; ++m) af[m] = *(const bf16x8*)(Al + (m * 16 + l15) * 64 + kx0);
      if (t + 1 < NT) stgB(q ^ 1, 0, t + 1);
      __builtin_amdgcn_s_barrier();
      __builtin_amdgcn_s_setprio(1);
#pragma unroll
      for (int m = 0; m < MH; ++m)
#pragma unroll
        for (int n = 0; n < 4; ++n)
          acc[m][n] = __builtin_amdgcn_mfma_f32_16x16x32_bf16(af[m], bf[n], acc[m][n], 0, 0, 0);
      __builtin_amdgcn_s_setprio(0);
      __builtin_amdgcn_s_barrier();

      // ph2: kslice0, m-half 1
#pragma unroll
      for (int m = 0; m < MH; ++m) af[m] = *(const bf16x8*)(Al + ((MH + m) * 16 + l15) * 64 + kx0);
      if (t + 1 < NT) stgB(q ^ 1, 1, t + 1);
      __builtin_amdgcn_s_barrier();
      __builtin_amdgcn_s_setprio(1);
#pragma unroll
      for (int m = 0; m < MH; ++m)
#pragma unroll
        for (int n = 0; n < 4; ++n)
          acc[MH + m][n] = __builtin_amdgcn_mfma_f32_16x16x32_bf16(af[m], bf[n], acc[MH + m][n], 0, 0, 0);
      __builtin_amdgcn_s_setprio(0);
      __builtin_amdgcn_s_barrier();

      // ph3: kslice1, m-half 0
#pragma unroll
      for (int n = 0; n < 4; ++n) bf[n] = *(const bf16x8*)(Bl + (n * 16 + l15) * 64 + kx1);
#pragma unroll
      for (int m = 0; m < MH; ++m) af[m] = *(const bf16x8*)(Al + (m * 16 + l15) * 64 + kx1);
      __builtin_amdgcn_s_barrier();
      __builtin_amdgcn_s_setprio(1);
#pragma unroll
      for (int m = 0; m < MH; ++m)
#pragma unroll
        for (int n = 0; n < 4; ++n)
          acc[m][n] = __builtin_amdgcn_mfma_f32_16x16x32_bf16(af[m], bf[n], acc[m][n], 0, 0, 0);
      __builtin_amdgcn_s_setprio(0);
      __builtin_amdgcn_s_barrier();

      // ph4: kslice1, m-half 1; stage A(t+2)
#pragma unroll
      for (int m = 0; m < MH; ++m) af[m] = *(const bf16x8*)(Al + ((MH + m) * 16 + l15) * 64 + kx1);
      __builtin_amdgcn_sched_barrier(0);
      if (t + 2 < NT) { stgA(q, 0, t + 2); stgA(q, 1, t + 2); }
      __builtin_amdgcn_s_barrier();
      __builtin_amdgcn_s_setprio(1);
#pragma unroll
      for (int m = 0; m < MH; ++m)
#pragma unroll
        for (int n = 0; n < 4; ++n)
          acc[MH + m][n] = __builtin_amdgcn_mfma_f32_16x16x32_bf16(af[m], bf[n], acc[MH + m][n], 0, 0, 0);
      __builtin_amdgcn_s_setprio(0);
      if (t < NT - 2)       asm volatile("s_waitcnt vmcnt(4)" ::: "memory");
      else if (t == NT - 2) asm volatile("s_waitcnt vmcnt(0)" ::: "memory");
      __builtin_amdgcn_s_barrier();
    }
  }

  // epilogue: C/D layout col=lane&15, row=(lane>>4)*4+j
  const int r4 = (lane >> 4) * 4;
  const long long crow0 = (long long)by * BM + wr * (BM / 2);
  const int ccol0 = bx * 256 + wc * 64;
#pragma unroll
  for (int n = 0; n < 4; ++n) {
    const int cg = ccol0 + n * 16 + l15;
    const float badd = bias ? bias[cg] : 0.f;
    ushort_t* outp = (ushort_t*)C0;
    int col = cg;
    if constexpr (MODE == 2) {
      const int sel = cg >> 10;
      col = cg & 1023;
      outp = (ushort_t*)(sel == 0 ? C0 : (sel == 1 ? C1 : C2));
    }
#pragma unroll
    for (int m = 0; m < MF; ++m)
#pragma unroll
      for (int j = 0; j < 4; ++j) {
        const long long rg = crow0 + m * 16 + r4 + j;
        const float v = acc[m][n][j] * scale + badd;
        if constexpr (MODE == 0)
          ((float*)C0)[(long long)z * sCz + rg * ldc + cg] = v;
        else if constexpr (MODE == 1)
          ((ushort_t*)C0)[(long long)z * sCz + rg * ldc + cg] = f2bf(v);
        else
          outp[rg * 1024 + col] = f2bf(v);
      }
  }
}

// ---------------------------------------------------------------------------
__global__ __launch_bounds__(256)
void cast_f32_bf16(const float* __restrict__ in, ushort_t* __restrict__ out, long long n)
{
  long long i = ((long long)blockIdx.x * blockDim.x + threadIdx.x) * 4;
  const long long stride = (long long)gridDim.x * blockDim.x * 4;
  for (; i < n; i += stride) {
    const float4 v = *(const float4*)&in[i];
    ushort4 o;
    o.x = f2bf(v.x); o.y = f2bf(v.y); o.z = f2bf(v.z); o.w = f2bf(v.w);
    *(ushort4*)&out[i] = o;
  }
}

// cast 3 weight matrices into concatenated w3 [3072][1024] + bias concat [3072]
__global__ __launch_bounds__(256)
void prep_w(const float* __restrict__ Wq, const float* __restrict__ Wk,
            const float* __restrict__ Wv, const float* __restrict__ bq,
            const float* __restrict__ bk, const float* __restrict__ bv,
            ushort_t* __restrict__ w3, float* __restrict__ bcat)
{
  const int which = blockIdx.x >> 10;
  const float* W = (which == 0) ? Wq : (which == 1) ? Wk : Wv;
  const long long i = ((long long)(blockIdx.x & 1023) * 256 + threadIdx.x) * 4;
  const float4 v = *(const float4*)&W[i];
  ushort4 o;
  o.x = f2bf(v.x); o.y = f2bf(v.y); o.z = f2bf(v.z); o.w = f2bf(v.w);
  *(ushort4*)&w3[(long long)which * 1024 * 1024 + i] = o;
  const int g = blockIdx.x * 256 + threadIdx.x;
  if (g < 3072) bcat[g] = (g < 1024) ? bq[g] : (g < 2048) ? bk[g - 1024] : bv[g - 2048];
}

// bf16 transpose per batch: in[z][rows][ldIn] -> out[z][cols][rows]
__global__ __launch_bounds__(256)
void transpose_bf16(const ushort_t* __restrict__ in, ushort_t* __restrict__ out,
                    int rows, int cols, int ldIn, long long sIn, long long sOut)
{
  __shared__ ushort_t t[64][65];
  in  += (long long)blockIdx.z * sIn;
  out += (long long)blockIdx.z * sOut;
  const int r0 = blockIdx.y * 64;
  const int c0 = blockIdx.x * 64;
  const int tx = threadIdx.x & 15, ty = threadIdx.x >> 4;
#pragma unroll
  for (int r = 0; r < 4; ++r) {
    const ushort4 v = *(const ushort4*)&in[(long long)(r0 + ty * 4 + r) * ldIn + c0 + tx * 4];
    t[ty * 4 + r][tx * 4 + 0] = v.x;
    t[ty * 4 + r][tx * 4 + 1] = v.y;
    t[ty * 4 + r][tx * 4 + 2] = v.z;
    t[ty * 4 + r][tx * 4 + 3] = v.w;
  }
  __syncthreads();
#pragma unroll
  for (int r = 0; r < 4; ++r) {
    const int d = ty * 4 + r;
    ushort4 v;
    v.x = t[tx * 4 + 0][d];
    v.y = t[tx * 4 + 1][d];
    v.z = t[tx * 4 + 2][d];
    v.w = t[tx * 4 + 3][d];
    *(ushort4*)&out[(long long)(c0 + d) * rows + r0 + tx * 4] = v;
  }
}

// row softmax over 2048 fp32 -> bf16, one block per row
__global__ __launch_bounds__(256)
void softmax2048(const float* __restrict__ Sc, ushort_t* __restrict__ P)
{
  const long long row = blockIdx.x;
  const float* s = Sc + row * 2048;
  const int tid = threadIdx.x;
  const int wave = tid >> 6, lane = tid & 63;

  const float4 a = *(const float4*)&s[tid * 4];
  const float4 b = *(const float4*)&s[1024 + tid * 4];
  float m = fmaxf(fmaxf(fmaxf(a.x, a.y), fmaxf(a.z, a.w)),
                  fmaxf(fmaxf(b.x, b.y), fmaxf(b.z, b.w)));
#pragma unroll
  for (int off = 32; off > 0; off >>= 1) m = fmaxf(m, __shfl_xor(m, off));
  __shared__ float redm[4], reds[4];
  if (lane == 0) redm[wave] = m;
  __syncthreads();
  m = fmaxf(fmaxf(redm[0], redm[1]), fmaxf(redm[2], redm[3]));

  float e[8];
  e[0] = __expf(a.x - m); e[1] = __expf(a.y - m); e[2] = __expf(a.z - m); e[3] = __expf(a.w - m);
  e[4] = __expf(b.x - m); e[5] = __expf(b.y - m); e[6] = __expf(b.z - m); e[7] = __expf(b.w - m);
  float sum = ((e[0] + e[1]) + (e[2] + e[3])) + ((e[4] + e[5]) + (e[6] + e[7]));
#pragma unroll
  for (int off = 32; off > 0; off >>= 1) sum += __shfl_xor(sum, off);
  if (lane == 0) reds[wave] = sum;
  __syncthreads();
  sum = (reds[0] + reds[1]) + (reds[2] + reds[3]);
  const float inv = 1.0f / sum;

  ushort4 o;
  o.x = f2bf(e[0] * inv); o.y = f2bf(e[1] * inv); o.z = f2bf(e[2] * inv); o.w = f2bf(e[3] * inv);
  *(ushort4*)&P[row * 2048 + tid * 4] = o;
  o.x = f2bf(e[4] * inv); o.y = f2bf(e[5] * inv); o.z = f2bf(e[6] * inv); o.w = f2bf(e[7] * inv);
  *(ushort4*)&P[row * 2048 + 1024 + tid * 4] = o;
}

// ---------------------------------------------------------------------------
extern "C" void kernel_launch(void* const* d_in, const int* in_sizes, int n_in,
                              void* d_out, int out_size, void* d_ws, size_t ws_size,
                              hipStream_t stream)
{
  constexpr int B = 4, S = 2048, D = 1024;
  constexpr long long MT = (long long)B * S;        // 8192 tokens
  constexpr long long SD = (long long)S * D;
  constexpr long long SS = (long long)S * S;

  const float* x  = (const float*)d_in[0];
  const float* Wq = (const float*)d_in[1];
  const float* bq = (const float*)d_in[2];
  const float* Wk = (const float*)d_in[3];
  const float* bk = (const float*)d_in[4];
  const float* Wv = (const float*)d_in[5];
  const float* bv = (const float*)d_in[6];
  float* out = (float*)d_out;

  // ws layout (bytes), total 167772160; xb/w3/bcat overlap scores (dead after proj)
  char* base = (char*)d_ws;
  ushort_t* q      = (ushort_t*)(base);               // 16777216
  ushort_t* k      = (ushort_t*)(base + 16777216);    // 16777216
  ushort_t* vt     = (ushort_t*)(base + 33554432);    // 16777216  [4][1024][2048]
  float*    scores = (float*)   (base + 50331648);    // 67108864
  ushort_t* P      = (ushort_t*)(base + 117440512);   // 33554432
  ushort_t* vplain = (ushort_t*)(base + 150994944);   // 16777216  [4][2048][1024]
  ushort_t* xb     = (ushort_t*)(base + 50331648);    // 16777216 (dead after proj)
  ushort_t* w3     = (ushort_t*)(base + 67108864);    // 6291456  (dead after proj)
  float*    bcat   = (float*)   (base + 73400320);    // 12288    (dead after proj)

  // 1) casts
  cast_f32_bf16<<<2048, 256, 0, stream>>>(x, xb, MT * D);
  prep_w<<<3072, 256, 0, stream>>>(Wq, Wk, Wv, bq, bk, bv, w3, bcat);

  // 2) fused QKV projection -> split q / k / vplain (contiguous, ld=1024)
  gemm8p<128, 2, 4, 8><<<dim3(12, 64, 1), 512, 0, stream>>>(
      xb, 0, D, w3, 0, D, q, k, vplain, 0, 1024, D, 1.f, bcat);

  // 3) v -> v^T per batch: [2048][1024] -> [1024][2048]
  transpose_bf16<<<dim3(16, 32, 4), 256, 0, stream>>>(
      vplain, vt, S, D, 1024, SD, SD);

  // 4) QK^T: scores[z] = (q @ k^T) / 32
  gemm8p<256, 0, 4, 2><<<dim3(8, 8, 4), 512, 0, stream>>>(
      q, SD, D, k, SD, D, scores, nullptr, nullptr, SS, S, D, 0.03125f, nullptr);

  // 5) softmax rows
  softmax2048<<<MT, 256, 0, stream>>>(scores, P);

  // 6) PV: out[z] = P @ vt^T
  gemm8p<128, 0, 2, 4><<<dim3(4, 16, 4), 512, 0, stream>>>(
      P, SS, S, vt, (long long)D * S, S, out, nullptr, nullptr, SD, D, S, 1.f, nullptr);
}

// Round 6
// 175.827 us; speedup vs baseline: 1.3750x; 1.0524x over previous
//
#include <hip/hip_runtime.h>

// Attention_13632226198096: B=4, S=2048, D=1024 fp32 single-head attention.
// Round 6: proj & PV -> 128x128 tile, 64 KB LDS, 2 blocks/CU (cross-block
// overlap hides staging); v^T fused into proj epilogue (transpose kernel
// deleted). QK keeps 256x256 4-phase. Conflict-free row&7 XOR LDS swizzle,
// per-GEMM XCD rects.

typedef unsigned short ushort_t;
typedef __bf16 bf16x8 __attribute__((ext_vector_type(8)));
typedef float f32x4 __attribute__((ext_vector_type(4)));

__device__ __forceinline__ unsigned short f2bf(float f) {
  unsigned u = __builtin_bit_cast(unsigned, f);
  u += 0x7fffu + ((u >> 16) & 1u);
  return (unsigned short)(u >> 16);
}

// ---------------------------------------------------------------------------
// 128x128 tile, BK=64, 512 thr = 8 waves (2M x 4N), per-wave 64x32 out.
// LDS: dbuf x (A 128x64 + B 128x64) = 64 KB -> 2 blocks/CU.
// 2 phases/K-tile: ph1 {all A + B-k0 reads, stage B(t+1), 8 MFMA},
//                  ph2 {B-k1 reads, stage A(t+2), 8 MFMA}; vmcnt(2)/tile.
// MODE 0: fp32 C0 [ldc=1024]. MODE 2: proj split -> q/k scatter bf16,
//         v written TRANSPOSED into vt[4][1024][2048].
// ---------------------------------------------------------------------------
template<int MODE, int RX, int RY>
__global__ __launch_bounds__(512, 4)
void gemm128(const ushort_t* __restrict__ A, long long sAz, int lda,
             const ushort_t* __restrict__ Bm, long long sBz, int ldb,
             void* __restrict__ C0, void* __restrict__ C1, void* __restrict__ C2,
             long long sCz, int ldc, int K, float scale, const float* __restrict__ bias)
{
  constexpr int SLOT = 8192;            // 128x64 elems
  constexpr int BUF  = 2 * SLOT;        // A+B per stage
  __shared__ ushort_t lds_[2 * BUF] __attribute__((aligned(16)));

  // XCD-aware bijective rect swizzle (per z-slice)
  constexpr int BPR = RX * RY;
  const int gx = gridDim.x;
  const int lin = blockIdx.y * gx + blockIdx.x;
  const int xcd = lin & 7, s = lin >> 3;
  const int chunk = s / BPR, idx = s % BPR;
  const int rect = chunk * 8 + xcd;
  const int nrx = gx / RX;
  const int bx = (rect % nrx) * RX + (idx % RX);
  const int by = (rect / nrx) * RY + (idx / RX);

  const int z = blockIdx.z;
  const ushort_t* Ab = A  + (long long)z * sAz + (long long)by * 128 * lda;
  const ushort_t* Bb = Bm + (long long)z * sBz + (long long)bx * 128 * ldb;

  const int tid = threadIdx.x, wid = tid >> 6, lane = tid & 63;
  const int wr = wid >> 2, wc = wid & 3;
  const int l15 = lane & 15;
  const int kx0 = (((lane >> 4) + 0) ^ (l15 & 7)) * 8;
  const int kx1 = (((lane >> 4) + 4) ^ (l15 & 7)) * 8;
  const int srow = lane >> 3;
  const int scol = ((lane & 7) ^ (srow & 7)) * 8;

  auto stg = [&](int mat, int q, int t) {
    const ushort_t* g0 = (mat == 0 ? Ab : Bb);
    const int ld = (mat == 0 ? lda : ldb);
#pragma unroll
    for (int j = 0; j < 2; ++j) {
      const ushort_t* g = g0 + (long long)(j * 64 + wid * 8 + srow) * ld + t * 64 + scol;
      __builtin_amdgcn_global_load_lds(
          (const __attribute__((address_space(1))) void*)g,
          (__attribute__((address_space(3))) void*)
            (&lds_[q * BUF + mat * SLOT + (j * 64 + wid * 8) * 64]),
          16, 0, 0);
    }
  };

  f32x4 acc[4][2];
#pragma unroll
  for (int m = 0; m < 4; ++m)
#pragma unroll
    for (int n = 0; n < 2; ++n)
#pragma unroll
      for (int j = 0; j < 4; ++j) acc[m][n][j] = 0.f;

  // prologue: A0 B0 A1
  stg(0, 0, 0); stg(1, 0, 0); stg(0, 1, 1);
  asm volatile("s_waitcnt vmcnt(2)" ::: "memory");
  __builtin_amdgcn_s_barrier();

  const int NT = K >> 6;
  bf16x8 a0[4], a1[4], bf[2];

  for (int t = 0; t < NT; ++t) {
    const int q = t & 1;
    const ushort_t* Al = &lds_[q * BUF] + wr * 64 * 64;
    const ushort_t* Bl = &lds_[q * BUF + SLOT] + wc * 32 * 64;

    // ph1: all A frags + B k0; stage B(t+1)
#pragma unroll
    for (int m = 0; m < 4; ++m) a0[m] = *(const bf16x8*)(Al + (m * 16 + l15) * 64 + kx0);
#pragma unroll
    for (int n = 0; n < 2; ++n) bf[n] = *(const bf16x8*)(Bl + (n * 16 + l15) * 64 + kx0);
#pragma unroll
    for (int m = 0; m < 4; ++m) a1[m] = *(const bf16x8*)(Al + (m * 16 + l15) * 64 + kx1);
    __builtin_amdgcn_sched_barrier(0);
    if (t + 1 < NT) stg(1, q ^ 1, t + 1);
    __builtin_amdgcn_s_barrier();
    __builtin_amdgcn_s_setprio(1);
#pragma unroll
    for (int m = 0; m < 4; ++m)
#pragma unroll
      for (int n = 0; n < 2; ++n)
        acc[m][n] = __builtin_amdgcn_mfma_f32_16x16x32_bf16(a0[m], bf[n], acc[m][n], 0, 0, 0);
    __builtin_amdgcn_s_setprio(0);
    __builtin_amdgcn_s_barrier();

    // ph2: B k1; stage A(t+2)
#pragma unroll
    for (int n = 0; n < 2; ++n) bf[n] = *(const bf16x8*)(Bl + (n * 16 + l15) * 64 + kx1);
    __builtin_amdgcn_sched_barrier(0);
    if (t + 2 < NT) stg(0, q, t + 2);
    __builtin_amdgcn_s_barrier();
    __builtin_amdgcn_s_setprio(1);
#pragma unroll
    for (int m = 0; m < 4; ++m)
#pragma unroll
      for (int n = 0; n < 2; ++n)
        acc[m][n] = __builtin_amdgcn_mfma_f32_16x16x32_bf16(a1[m], bf[n], acc[m][n], 0, 0, 0);
    __builtin_amdgcn_s_setprio(0);
    if (t < NT - 2)       asm volatile("s_waitcnt vmcnt(2)" ::: "memory");
    else if (t == NT - 2) asm volatile("s_waitcnt vmcnt(0)" ::: "memory");
    __builtin_amdgcn_s_barrier();
  }

  // epilogue: C/D layout col=lane&15, row=(lane>>4)*4+j
  const int r4 = (lane >> 4) * 4;
  const long long crow0 = (long long)by * 128 + wr * 64;
  const int ccol0 = bx * 128 + wc * 32;

  if constexpr (MODE == 0) {
#pragma unroll
    for (int n = 0; n < 2; ++n) {
      const int cg = ccol0 + n * 16 + l15;
#pragma unroll
      for (int m = 0; m < 4; ++m)
#pragma unroll
        for (int j = 0; j < 4; ++j) {
          const long long rg = crow0 + m * 16 + r4 + j;
          ((float*)C0)[(long long)z * sCz + rg * ldc + cg] = acc[m][n][j] * scale;
        }
    }
  } else {
    // MODE 2: proj. sel uniform per block (BN=128 within one 1024-col group)
    const int sel = ccol0 >> 10;
#pragma unroll
    for (int n = 0; n < 2; ++n) {
      const int cg = ccol0 + n * 16 + l15;
      const int col = cg & 1023;
      const float badd = bias[cg];
      if (sel < 2) {
        ushort_t* outp = (ushort_t*)(sel == 0 ? C0 : C1);
#pragma unroll
        for (int m = 0; m < 4; ++m)
#pragma unroll
          for (int j = 0; j < 4; ++j) {
            const long long rg = crow0 + m * 16 + r4 + j;
            outp[rg * 1024 + col] = f2bf(acc[m][n][j] + badd);
          }
      } else {
        // v -> vt[b][col][s], 4 consecutive s per lane => ushort4
        ushort_t* vt = (ushort_t*)C2;
#pragma unroll
        for (int m = 0; m < 4; ++m) {
          const long long rg = crow0 + m * 16 + r4;
          const long long b = rg >> 11, srw = rg & 2047;
          ushort4 o;
          o.x = f2bf(acc[m][n][0] + badd);
          o.y = f2bf(acc[m][n][1] + badd);
          o.z = f2bf(acc[m][n][2] + badd);
          o.w = f2bf(acc[m][n][3] + badd);
          *(ushort4*)&vt[b * 2097152 + (long long)col * 2048 + srw] = o;
        }
      }
    }
  }
}

// ---------------------------------------------------------------------------
// 256x256 tile, 4-phase (unchanged from r5, QK only): fp32 out, scale.
// ---------------------------------------------------------------------------
__global__ __launch_bounds__(512, 1)
void gemm256(const ushort_t* __restrict__ A, long long sAz, int lda,
             const ushort_t* __restrict__ Bm, long long sBz, int ldb,
             float* __restrict__ C, long long sCz, int ldc,
             int K, float scale)
{
  constexpr int AH = 8192, BH = 8192, BUF = 2 * AH + 2 * BH;
  constexpr int RX = 4, RY = 2, BPR = RX * RY;
  __shared__ ushort_t lds_[2 * BUF] __attribute__((aligned(16)));

  const int gx = gridDim.x;
  const int lin = blockIdx.y * gx + blockIdx.x;
  const int xcd = lin & 7, s = lin >> 3;
  const int chunk = s / BPR, idx = s % BPR;
  const int rect = chunk * 8 + xcd;
  const int nrx = gx / RX;
  const int bx = (rect % nrx) * RX + (idx % RX);
  const int by = (rect / nrx) * RY + (idx / RX);

  const int z = blockIdx.z;
  const ushort_t* Ab = A  + (long long)z * sAz + (long long)by * 256 * lda;
  const ushort_t* Bb = Bm + (long long)z * sBz + (long long)bx * 256 * ldb;

  const int tid = threadIdx.x, wid = tid >> 6, lane = tid & 63;
  const int wr = wid >> 2, wc = wid & 3;
  const int l15 = lane & 15;
  const int kx0 = (((lane >> 4) + 0) ^ (l15 & 7)) * 8;
  const int kx1 = (((lane >> 4) + 4) ^ (l15 & 7)) * 8;
  const int srow = lane >> 3;
  const int scol = ((lane & 7) ^ (srow & 7)) * 8;

  auto stgA = [&](int q, int h, int t) {
#pragma unroll
    for (int j = 0; j < 2; ++j) {
      const ushort_t* g = Ab + (long long)(h * 128 + wid * 16 + j * 8 + srow) * lda
                             + t * 64 + scol;
      __builtin_amdgcn_global_load_lds(
          (const __attribute__((address_space(1))) void*)g,
          (__attribute__((address_space(3))) void*)
            (&lds_[q * BUF + h * AH + (wid * 128 + j * 64) * 8]),
          16, 0, 0);
    }
  };
  auto stgB = [&](int q, int h, int t) {
#pragma unroll
    for (int j = 0; j < 2; ++j) {
      const ushort_t* g = Bb + (long long)(h * 128 + wid * 16 + j * 8 + srow) * ldb
                             + t * 64 + scol;
      __builtin_amdgcn_global_load_lds(
          (const __attribute__((address_space(1))) void*)g,
          (__attribute__((address_space(3))) void*)
            (&lds_[q * BUF + 2 * AH + h * BH + (wid * 128 + j * 64) * 8]),
          16, 0, 0);
    }
  };

  f32x4 acc[8][4];
#pragma unroll
  for (int m = 0; m < 8; ++m)
#pragma unroll
    for (int n = 0; n < 4; ++n)
#pragma unroll
      for (int j = 0; j < 4; ++j) acc[m][n][j] = 0.f;

  stgA(0, 0, 0); stgA(0, 1, 0);
  stgB(0, 0, 0); stgB(0, 1, 0);
  stgA(1, 0, 1); stgA(1, 1, 1);
  asm volatile("s_waitcnt vmcnt(4)" ::: "memory");
  __builtin_amdgcn_s_barrier();

  const int NT = K >> 6;
  bf16x8 af[4], bf[4];

  for (int t = 0; t < NT; ++t) {
    const int q = t & 1;
    const ushort_t* Al = &lds_[q * BUF + wr * AH];
    const ushort_t* Bl = &lds_[q * BUF + 2 * AH + (wc >> 1) * BH + (wc & 1) * 4096];

    // ph1: k0, m-half 0 + all B@k0
#pragma unroll
    for (int n = 0; n < 4; ++n) bf[n] = *(const bf16x8*)(Bl + (n * 16 + l15) * 64 + kx0);
#pragma unroll
    for (int m = 0; m < 4; ++m) af[m] = *(const bf16x8*)(Al + (m * 16 + l15) * 64 + kx0);
    if (t + 1 < NT) stgB(q ^ 1, 0, t + 1);
    __builtin_amdgcn_s_barrier();
    __builtin_amdgcn_s_setprio(1);
#pragma unroll
    for (int m = 0; m < 4; ++m)
#pragma unroll
      for (int n = 0; n < 4; ++n)
        acc[m][n] = __builtin_amdgcn_mfma_f32_16x16x32_bf16(af[m], bf[n], acc[m][n], 0, 0, 0);
    __builtin_amdgcn_s_setprio(0);
    __builtin_amdgcn_s_barrier();

    // ph2: k0, m-half 1
#pragma unroll
    for (int m = 0; m < 4; ++m) af[m] = *(const bf16x8*)(Al + ((4 + m) * 16 + l15) * 64 + kx0);
    if (t + 1 < NT) stgB(q ^ 1, 1, t + 1);
    __builtin_amdgcn_s_barrier();
    __builtin_amdgcn_s_setprio(1);
#pragma unroll
    for (int m = 0; m < 4; ++m)
#pragma unroll
      for (int n = 0; n < 4; ++n)
        acc[4 + m][n] = __builtin_amdgcn_mfma_f32_16x16x32_bf16(af[m], bf[n], acc[4 + m][n], 0, 0, 0);
    __builtin_amdgcn_s_setprio(0);
    __builtin_amdgcn_s_barrier();

    // ph3: k1, m-half 0
#pragma unroll
    for (int n = 0; n < 4; ++n) bf[n] = *(const bf16x8*)(Bl + (n * 16 + l15) * 64 + kx1);
#pragma unroll
    for (int m = 0; m < 4; ++m) af[m] = *(const bf16x8*)(Al + (m * 16 + l15) * 64 + kx1);
    __builtin_amdgcn_s_barrier();
    __builtin_amdgcn_s_setprio(1);
#pragma unroll
    for (int m = 0; m < 4; ++m)
#pragma unroll
      for (int n = 0; n < 4; ++n)
        acc[m][n] = __builtin_amdgcn_mfma_f32_16x16x32_bf16(af[m], bf[n], acc[m][n], 0, 0, 0);
    __builtin_amdgcn_s_setprio(0);
    __builtin_amdgcn_s_barrier();

    // ph4: k1, m-half 1; stage A(t+2)
#pragma unroll
    for (int m = 0; m < 4; ++m) af[m] = *(const bf16x8*)(Al + ((4 + m) * 16 + l15) * 64 + kx1);
    __builtin_amdgcn_sched_barrier(0);
    if (t + 2 < NT) { stgA(q, 0, t + 2); stgA(q, 1, t + 2); }
    __builtin_amdgcn_s_barrier();
    __builtin_amdgcn_s_setprio(1);
#pragma unroll
    for (int m = 0; m < 4; ++m)
#pragma unroll
      for (int n = 0; n < 4; ++n)
        acc[4 + m][n] = __builtin_amdgcn_mfma_f32_16x16x32_bf16(af[m], bf[n], acc[4 + m][n], 0, 0, 0);
    __builtin_amdgcn_s_setprio(0);
    if (t < NT - 2)       asm volatile("s_waitcnt vmcnt(4)" ::: "memory");
    else if (t == NT - 2) asm volatile("s_waitcnt vmcnt(0)" ::: "memory");
    __builtin_amdgcn_s_barrier();
  }

  const int r4 = (lane >> 4) * 4;
  const long long crow0 = (long long)by * 256 + wr * 128;
  const int ccol0 = bx * 256 + wc * 64;
#pragma unroll
  for (int n = 0; n < 4; ++n) {
    const int cg = ccol0 + n * 16 + l15;
#pragma unroll
    for (int m = 0; m < 8; ++m)
#pragma unroll
      for (int j = 0; j < 4; ++j) {
        const long long rg = crow0 + m * 16 + r4 + j;
        C[(long long)z * sCz + rg * ldc + cg] = acc[m][n][j] * scale;
      }
  }
}

// ---------------------------------------------------------------------------
__global__ __launch_bounds__(256)
void cast_f32_bf16(const float* __restrict__ in, ushort_t* __restrict__ out, long long n)
{
  long long i = ((long long)blockIdx.x * blockDim.x + threadIdx.x) * 4;
  const long long stride = (long long)gridDim.x * blockDim.x * 4;
  for (; i < n; i += stride) {
    const float4 v = *(const float4*)&in[i];
    ushort4 o;
    o.x = f2bf(v.x); o.y = f2bf(v.y); o.z = f2bf(v.z); o.w = f2bf(v.w);
    *(ushort4*)&out[i] = o;
  }
}

// cast 3 weight matrices into concatenated w3 [3072][1024] + bias concat [3072]
__global__ __launch_bounds__(256)
void prep_w(const float* __restrict__ Wq, const float* __restrict__ Wk,
            const float* __restrict__ Wv, const float* __restrict__ bq,
            const float* __restrict__ bk, const float* __restrict__ bv,
            ushort_t* __restrict__ w3, float* __restrict__ bcat)
{
  const int which = blockIdx.x >> 10;
  const float* W = (which == 0) ? Wq : (which == 1) ? Wk : Wv;
  const long long i = ((long long)(blockIdx.x & 1023) * 256 + threadIdx.x) * 4;
  const float4 v = *(const float4*)&W[i];
  ushort4 o;
  o.x = f2bf(v.x); o.y = f2bf(v.y); o.z = f2bf(v.z); o.w = f2bf(v.w);
  *(ushort4*)&w3[(long long)which * 1024 * 1024 + i] = o;
  const int g = blockIdx.x * 256 + threadIdx.x;
  if (g < 3072) bcat[g] = (g < 1024) ? bq[g] : (g < 2048) ? bk[g - 1024] : bv[g - 2048];
}

// row softmax over 2048 fp32 -> bf16, one block per row
__global__ __launch_bounds__(256)
void softmax2048(const float* __restrict__ Sc, ushort_t* __restrict__ P)
{
  const long long row = blockIdx.x;
  const float* s = Sc + row * 2048;
  const int tid = threadIdx.x;
  const int wave = tid >> 6, lane = tid & 63;

  const float4 a = *(const float4*)&s[tid * 4];
  const float4 b = *(const float4*)&s[1024 + tid * 4];
  float m = fmaxf(fmaxf(fmaxf(a.x, a.y), fmaxf(a.z, a.w)),
                  fmaxf(fmaxf(b.x, b.y), fmaxf(b.z, b.w)));
#pragma unroll
  for (int off = 32; off > 0; off >>= 1) m = fmaxf(m, __shfl_xor(m, off));
  __shared__ float redm[4], reds[4];
  if (lane == 0) redm[wave] = m;
  __syncthreads();
  m = fmaxf(fmaxf(redm[0], redm[1]), fmaxf(redm[2], redm[3]));

  float e[8];
  e[0] = __expf(a.x - m); e[1] = __expf(a.y - m); e[2] = __expf(a.z - m); e[3] = __expf(a.w - m);
  e[4] = __expf(b.x - m); e[5] = __expf(b.y - m); e[6] = __expf(b.z - m); e[7] = __expf(b.w - m);
  float sum = ((e[0] + e[1]) + (e[2] + e[3])) + ((e[4] + e[5]) + (e[6] + e[7]));
#pragma unroll
  for (int off = 32; off > 0; off >>= 1) sum += __shfl_xor(sum, off);
  if (lane == 0) reds[wave] = sum;
  __syncthreads();
  sum = (reds[0] + reds[1]) + (reds[2] + reds[3]);
  const float inv = 1.0f / sum;

  ushort4 o;
  o.x = f2bf(e[0] * inv); o.y = f2bf(e[1] * inv); o.z = f2bf(e[2] * inv); o.w = f2bf(e[3] * inv);
  *(ushort4*)&P[row * 2048 + tid * 4] = o;
  o.x = f2bf(e[4] * inv); o.y = f2bf(e[5] * inv); o.z = f2bf(e[6] * inv); o.w = f2bf(e[7] * inv);
  *(ushort4*)&P[row * 2048 + 1024 + tid * 4] = o;
}

// ---------------------------------------------------------------------------
extern "C" void kernel_launch(void* const* d_in, const int* in_sizes, int n_in,
                              void* d_out, int out_size, void* d_ws, size_t ws_size,
                              hipStream_t stream)
{
  constexpr int B = 4, S = 2048, D = 1024;
  constexpr long long MT = (long long)B * S;        // 8192 tokens
  constexpr long long SD = (long long)S * D;
  constexpr long long SS = (long long)S * S;

  const float* x  = (const float*)d_in[0];
  const float* Wq = (const float*)d_in[1];
  const float* bq = (const float*)d_in[2];
  const float* Wk = (const float*)d_in[3];
  const float* bk = (const float*)d_in[4];
  const float* Wv = (const float*)d_in[5];
  const float* bv = (const float*)d_in[6];
  float* out = (float*)d_out;

  // ws layout (bytes); xb/w3/bcat overlap scores (dead after proj)
  char* base = (char*)d_ws;
  ushort_t* q      = (ushort_t*)(base);               // 16777216
  ushort_t* k      = (ushort_t*)(base + 16777216);    // 16777216
  ushort_t* vt     = (ushort_t*)(base + 33554432);    // 16777216  [4][1024][2048]
  float*    scores = (float*)   (base + 50331648);    // 67108864
  ushort_t* P      = (ushort_t*)(base + 117440512);   // 33554432  (end 150994944)
  ushort_t* xb     = (ushort_t*)(base + 50331648);    // 16777216 (dead after proj)
  ushort_t* w3     = (ushort_t*)(base + 67108864);    // 6291456  (dead after proj)
  float*    bcat   = (float*)   (base + 73400320);    // 12288    (dead after proj)

  // 1) casts
  cast_f32_bf16<<<2048, 256, 0, stream>>>(x, xb, MT * D);
  prep_w<<<3072, 256, 0, stream>>>(Wq, Wk, Wv, bq, bk, bv, w3, bcat);

  // 2) fused QKV projection -> q, k (plain) + vt (transposed), bias fused
  gemm128<2, 4, 8><<<dim3(24, 64, 1), 512, 0, stream>>>(
      xb, 0, D, w3, 0, D, q, k, vt, 0, 1024, D, 1.f, bcat);

  // 3) QK^T: scores[z] = (q @ k^T) / 32
  gemm256<<<dim3(8, 8, 4), 512, 0, stream>>>(
      q, SD, D, k, SD, D, scores, SS, S, D, 0.03125f);

  // 4) softmax rows
  softmax2048<<<MT, 256, 0, stream>>>(scores, P);

  // 5) PV: out[z] = P @ vt^T
  gemm128<0, 2, 4><<<dim3(8, 16, 4), 512, 0, stream>>>(
      P, SS, S, vt, (long long)D * S, S, out, nullptr, nullptr, SD, D, S, 1.f, nullptr);
}

// Round 8
// 168.627 us; speedup vs baseline: 1.4337x; 1.0427x over previous
//
#include <hip/hip_runtime.h>

// Attention_13632226198096: B=4, S=2048, D=1024 fp32 single-head attention.
// Round 8: r7 + race fix — lgkmcnt(0) fence before in-loop stage issues so
// ds_reads of the live LDS buffer complete before any overwriting
// global_load_lds can land (r7's replay divergence was this race).
// proj & PV: 128x128 2-phase, 64 KB LDS, 2 blocks/CU. QK: 256x256 4-phase.
// fp16 scores; conflict-free row&7 XOR LDS swizzle; per-GEMM XCD rects.

typedef unsigned short ushort_t;
typedef __bf16 bf16x8 __attribute__((ext_vector_type(8)));
typedef float f32x4 __attribute__((ext_vector_type(4)));
typedef _Float16 h8 __attribute__((ext_vector_type(8)));
typedef short short8v __attribute__((ext_vector_type(8)));

__device__ __forceinline__ unsigned short f2bf(float f) {
  unsigned u = __builtin_bit_cast(unsigned, f);
  u += 0x7fffu + ((u >> 16) & 1u);
  return (unsigned short)(u >> 16);
}

// ---------------------------------------------------------------------------
// 128x128 tile, BK=64, 512 thr = 8 waves (2M x 4N), per-wave 64x32 out.
// LDS: dbuf x (A 128x64 + B 128x64) = 64 KB -> 2 blocks/CU.
// 2 phases/K-tile; A(t+2)+B(t+2) staged at end of ph2 AFTER lgkm drain;
// vmcnt(4) at tile end. MODE 0: fp32 C0. MODE 2: q/k bf16 + v^T into vt.
// ---------------------------------------------------------------------------
template<int MODE, int RX, int RY>
__global__ __launch_bounds__(512, 4)
void gemm128(const ushort_t* __restrict__ A, long long sAz, int lda,
             const ushort_t* __restrict__ Bm, long long sBz, int ldb,
             void* __restrict__ C0, void* __restrict__ C1, void* __restrict__ C2,
             long long sCz, int ldc, int K, float scale, const float* __restrict__ bias)
{
  constexpr int SLOT = 8192;            // 128x64 elems
  constexpr int BUF  = 2 * SLOT;
  __shared__ ushort_t lds_[2 * BUF] __attribute__((aligned(16)));

  constexpr int BPR = RX * RY;
  const int gx = gridDim.x;
  const int lin = blockIdx.y * gx + blockIdx.x;
  const int xcd = lin & 7, s = lin >> 3;
  const int chunk = s / BPR, idx = s % BPR;
  const int rect = chunk * 8 + xcd;
  const int nrx = gx / RX;
  const int bx = (rect % nrx) * RX + (idx % RX);
  const int by = (rect / nrx) * RY + (idx / RX);

  const int z = blockIdx.z;
  const ushort_t* Ab = A  + (long long)z * sAz + (long long)by * 128 * lda;
  const ushort_t* Bb = Bm + (long long)z * sBz + (long long)bx * 128 * ldb;

  const int tid = threadIdx.x, wid = tid >> 6, lane = tid & 63;
  const int wr = wid >> 2, wc = wid & 3;
  const int l15 = lane & 15;
  const int kx0 = (((lane >> 4) + 0) ^ (l15 & 7)) * 8;
  const int kx1 = (((lane >> 4) + 4) ^ (l15 & 7)) * 8;
  const int srow = lane >> 3;
  const int scol = ((lane & 7) ^ (srow & 7)) * 8;

  // staging pointers, advanced by 64 per staged tile
  const ushort_t* agA = Ab + (long long)(wid * 8 + srow) * lda + scol;
  const ushort_t* agB = Bb + (long long)(wid * 8 + srow) * ldb + scol;
  const long long jA = (long long)64 * lda, jB = (long long)64 * ldb;
  const int ldsA0 = wid * 512;          // + q*BUF + j*4096
  const int ldsB0 = SLOT + wid * 512;

  auto stage = [&](const ushort_t* g, long long jstep, int ldsOff) {
#pragma unroll
    for (int j = 0; j < 2; ++j)
      __builtin_amdgcn_global_load_lds(
          (const __attribute__((address_space(1))) void*)(g + j * jstep),
          (__attribute__((address_space(3))) void*)(&lds_[ldsOff + j * 4096]),
          16, 0, 0);
  };

  f32x4 acc[4][2];
#pragma unroll
  for (int m = 0; m < 4; ++m)
#pragma unroll
    for (int n = 0; n < 2; ++n)
#pragma unroll
      for (int j = 0; j < 4; ++j) acc[m][n][j] = 0.f;

  // prologue: tiles 0 and 1 (A+B each)
  stage(agA, jA, 0 * BUF + ldsA0); agA += 64;
  stage(agB, jB, 0 * BUF + ldsB0); agB += 64;
  stage(agA, jA, 1 * BUF + ldsA0); agA += 64;
  stage(agB, jB, 1 * BUF + ldsB0); agB += 64;
  asm volatile("s_waitcnt vmcnt(4)" ::: "memory");
  __builtin_amdgcn_s_barrier();

  const int NT = K >> 6;
  bf16x8 a0[4], a1[4], bf[2];

  for (int t = 0; t < NT; ++t) {
    const int q = t & 1;
    const ushort_t* Al = &lds_[q * BUF] + wr * 4096;
    const ushort_t* Bl = &lds_[q * BUF + SLOT] + wc * 2048;

    // ph1: all A frags + B k0
#pragma unroll
    for (int m = 0; m < 4; ++m) a0[m] = *(const bf16x8*)(Al + (m * 16 + l15) * 64 + kx0);
#pragma unroll
    for (int n = 0; n < 2; ++n) bf[n] = *(const bf16x8*)(Bl + (n * 16 + l15) * 64 + kx0);
#pragma unroll
    for (int m = 0; m < 4; ++m) a1[m] = *(const bf16x8*)(Al + (m * 16 + l15) * 64 + kx1);
    __builtin_amdgcn_s_barrier();
    __builtin_amdgcn_s_setprio(1);
#pragma unroll
    for (int m = 0; m < 4; ++m)
#pragma unroll
      for (int n = 0; n < 2; ++n)
        acc[m][n] = __builtin_amdgcn_mfma_f32_16x16x32_bf16(a0[m], bf[n], acc[m][n], 0, 0, 0);
    __builtin_amdgcn_s_setprio(0);
    __builtin_amdgcn_s_barrier();

    // ph2: B k1; drain DS reads, THEN stage A(t+2)+B(t+2) into this buffer
#pragma unroll
    for (int n = 0; n < 2; ++n) bf[n] = *(const bf16x8*)(Bl + (n * 16 + l15) * 64 + kx1);
    asm volatile("s_waitcnt lgkmcnt(0)" ::: "memory");   // reads of buf q complete
    __builtin_amdgcn_sched_barrier(0);
    if (t + 2 < NT) {
      stage(agA, jA, q * BUF + ldsA0); agA += 64;
      stage(agB, jB, q * BUF + ldsB0); agB += 64;
    }
    __builtin_amdgcn_s_barrier();
    __builtin_amdgcn_s_setprio(1);
#pragma unroll
    for (int m = 0; m < 4; ++m)
#pragma unroll
      for (int n = 0; n < 2; ++n)
        acc[m][n] = __builtin_amdgcn_mfma_f32_16x16x32_bf16(a1[m], bf[n], acc[m][n], 0, 0, 0);
    __builtin_amdgcn_s_setprio(0);
    if (t < NT - 2)       asm volatile("s_waitcnt vmcnt(4)" ::: "memory");
    else if (t == NT - 2) asm volatile("s_waitcnt vmcnt(0)" ::: "memory");
    __builtin_amdgcn_s_barrier();
  }

  // epilogue: C/D layout col=lane&15, row=(lane>>4)*4+j
  const int r4 = (lane >> 4) * 4;
  const long long crow0 = (long long)by * 128 + wr * 64;
  const int ccol0 = bx * 128 + wc * 32;

  if constexpr (MODE == 0) {
#pragma unroll
    for (int n = 0; n < 2; ++n) {
      const int cg = ccol0 + n * 16 + l15;
#pragma unroll
      for (int m = 0; m < 4; ++m)
#pragma unroll
        for (int j = 0; j < 4; ++j) {
          const long long rg = crow0 + m * 16 + r4 + j;
          ((float*)C0)[(long long)z * sCz + rg * ldc + cg] = acc[m][n][j] * scale;
        }
    }
  } else {
    const int sel = ccol0 >> 10;
#pragma unroll
    for (int n = 0; n < 2; ++n) {
      const int cg = ccol0 + n * 16 + l15;
      const int col = cg & 1023;
      const float badd = bias[cg];
      if (sel < 2) {
        ushort_t* outp = (ushort_t*)(sel == 0 ? C0 : C1);
#pragma unroll
        for (int m = 0; m < 4; ++m)
#pragma unroll
          for (int j = 0; j < 4; ++j) {
            const long long rg = crow0 + m * 16 + r4 + j;
            outp[rg * 1024 + col] = f2bf(acc[m][n][j] + badd);
          }
      } else {
        ushort_t* vt = (ushort_t*)C2;
#pragma unroll
        for (int m = 0; m < 4; ++m) {
          const long long rg = crow0 + m * 16 + r4;
          const long long b = rg >> 11, srw = rg & 2047;
          ushort4 o;
          o.x = f2bf(acc[m][n][0] + badd);
          o.y = f2bf(acc[m][n][1] + badd);
          o.z = f2bf(acc[m][n][2] + badd);
          o.w = f2bf(acc[m][n][3] + badd);
          *(ushort4*)&vt[b * 2097152 + (long long)col * 2048 + srw] = o;
        }
      }
    }
  }
}

// ---------------------------------------------------------------------------
// 256x256 tile, 4-phase; fp16 output (QK scores). A(t+2)+B(t+2) staged in
// ph4 after lgkm drain; vmcnt(8) at tile end.
// ---------------------------------------------------------------------------
__global__ __launch_bounds__(512, 1)
void gemm256(const ushort_t* __restrict__ A, long long sAz, int lda,
             const ushort_t* __restrict__ Bm, long long sBz, int ldb,
             _Float16* __restrict__ C, long long sCz, int ldc,
             int K, float scale)
{
  constexpr int AH = 8192, BH = 8192, BUF = 2 * AH + 2 * BH;
  constexpr int RX = 4, RY = 2, BPR = RX * RY;
  __shared__ ushort_t lds_[2 * BUF] __attribute__((aligned(16)));

  const int gx = gridDim.x;
  const int lin = blockIdx.y * gx + blockIdx.x;
  const int xcd = lin & 7, s = lin >> 3;
  const int chunk = s / BPR, idx = s % BPR;
  const int rect = chunk * 8 + xcd;
  const int nrx = gx / RX;
  const int bx = (rect % nrx) * RX + (idx % RX);
  const int by = (rect / nrx) * RY + (idx / RX);

  const int z = blockIdx.z;
  const ushort_t* Ab = A  + (long long)z * sAz + (long long)by * 256 * lda;
  const ushort_t* Bb = Bm + (long long)z * sBz + (long long)bx * 256 * ldb;

  const int tid = threadIdx.x, wid = tid >> 6, lane = tid & 63;
  const int wr = wid >> 2, wc = wid & 3;
  const int l15 = lane & 15;
  const int kx0 = (((lane >> 4) + 0) ^ (l15 & 7)) * 8;
  const int kx1 = (((lane >> 4) + 4) ^ (l15 & 7)) * 8;
  const int srow = lane >> 3;
  const int scol = ((lane & 7) ^ (srow & 7)) * 8;

  const ushort_t* agA = Ab + (long long)(wid * 16 + srow) * lda + scol;
  const ushort_t* agB = Bb + (long long)(wid * 16 + srow) * ldb + scol;

  auto stageA = [&](int q) {
#pragma unroll
    for (int h = 0; h < 2; ++h)
#pragma unroll
      for (int j = 0; j < 2; ++j)
        __builtin_amdgcn_global_load_lds(
            (const __attribute__((address_space(1))) void*)(agA + (long long)(h * 128 + j * 8) * lda),
            (__attribute__((address_space(3))) void*)
              (&lds_[q * BUF + h * AH + (wid * 128 + j * 64) * 8]),
            16, 0, 0);
  };
  auto stageB = [&](int q) {
#pragma unroll
    for (int h = 0; h < 2; ++h)
#pragma unroll
      for (int j = 0; j < 2; ++j)
        __builtin_amdgcn_global_load_lds(
            (const __attribute__((address_space(1))) void*)(agB + (long long)(h * 128 + j * 8) * ldb),
            (__attribute__((address_space(3))) void*)
              (&lds_[q * BUF + 2 * AH + h * BH + (wid * 128 + j * 64) * 8]),
            16, 0, 0);
  };

  f32x4 acc[8][4];
#pragma unroll
  for (int m = 0; m < 8; ++m)
#pragma unroll
    for (int n = 0; n < 4; ++n)
#pragma unroll
      for (int j = 0; j < 4; ++j) acc[m][n][j] = 0.f;

  stageA(0); stageB(0); agA += 64; agB += 64;
  stageA(1); stageB(1); agA += 64; agB += 64;
  asm volatile("s_waitcnt vmcnt(8)" ::: "memory");
  __builtin_amdgcn_s_barrier();

  const int NT = K >> 6;
  bf16x8 af[4], bf[4];

  for (int t = 0; t < NT; ++t) {
    const int q = t & 1;
    const ushort_t* Al = &lds_[q * BUF + wr * AH];
    const ushort_t* Bl = &lds_[q * BUF + 2 * AH + (wc >> 1) * BH + (wc & 1) * 4096];

    // ph1: k0, m-half 0 + all B@k0
#pragma unroll
    for (int n = 0; n < 4; ++n) bf[n] = *(const bf16x8*)(Bl + (n * 16 + l15) * 64 + kx0);
#pragma unroll
    for (int m = 0; m < 4; ++m) af[m] = *(const bf16x8*)(Al + (m * 16 + l15) * 64 + kx0);
    __builtin_amdgcn_s_barrier();
    __builtin_amdgcn_s_setprio(1);
#pragma unroll
    for (int m = 0; m < 4; ++m)
#pragma unroll
      for (int n = 0; n < 4; ++n)
        acc[m][n] = __builtin_amdgcn_mfma_f32_16x16x32_bf16(af[m], bf[n], acc[m][n], 0, 0, 0);
    __builtin_amdgcn_s_setprio(0);
    __builtin_amdgcn_s_barrier();

    // ph2: k0, m-half 1
#pragma unroll
    for (int m = 0; m < 4; ++m) af[m] = *(const bf16x8*)(Al + ((4 + m) * 16 + l15) * 64 + kx0);
    __builtin_amdgcn_s_barrier();
    __builtin_amdgcn_s_setprio(1);
#pragma unroll
    for (int m = 0; m < 4; ++m)
#pragma unroll
      for (int n = 0; n < 4; ++n)
        acc[4 + m][n] = __builtin_amdgcn_mfma_f32_16x16x32_bf16(af[m], bf[n], acc[4 + m][n], 0, 0, 0);
    __builtin_amdgcn_s_setprio(0);
    __builtin_amdgcn_s_barrier();

    // ph3: k1, m-half 0
#pragma unroll
    for (int n = 0; n < 4; ++n) bf[n] = *(const bf16x8*)(Bl + (n * 16 + l15) * 64 + kx1);
#pragma unroll
    for (int m = 0; m < 4; ++m) af[m] = *(const bf16x8*)(Al + (m * 16 + l15) * 64 + kx1);
    __builtin_amdgcn_s_barrier();
    __builtin_amdgcn_s_setprio(1);
#pragma unroll
    for (int m = 0; m < 4; ++m)
#pragma unroll
      for (int n = 0; n < 4; ++n)
        acc[m][n] = __builtin_amdgcn_mfma_f32_16x16x32_bf16(af[m], bf[n], acc[m][n], 0, 0, 0);
    __builtin_amdgcn_s_setprio(0);
    __builtin_amdgcn_s_barrier();

    // ph4: k1, m-half 1; drain DS reads, THEN stage A(t+2)+B(t+2)
#pragma unroll
    for (int m = 0; m < 4; ++m) af[m] = *(const bf16x8*)(Al + ((4 + m) * 16 + l15) * 64 + kx1);
    asm volatile("s_waitcnt lgkmcnt(0)" ::: "memory");   // reads of buf q complete
    __builtin_amdgcn_sched_barrier(0);
    if (t + 2 < NT) { stageA(q); stageB(q); agA += 64; agB += 64; }
    __builtin_amdgcn_s_barrier();
    __builtin_amdgcn_s_setprio(1);
#pragma unroll
    for (int m = 0; m < 4; ++m)
#pragma unroll
      for (int n = 0; n < 4; ++n)
        acc[4 + m][n] = __builtin_amdgcn_mfma_f32_16x16x32_bf16(af[m], bf[n], acc[4 + m][n], 0, 0, 0);
    __builtin_amdgcn_s_setprio(0);
    if (t < NT - 2)       asm volatile("s_waitcnt vmcnt(8)" ::: "memory");
    else if (t == NT - 2) asm volatile("s_waitcnt vmcnt(0)" ::: "memory");
    __builtin_amdgcn_s_barrier();
  }

  const int r4 = (lane >> 4) * 4;
  const long long crow0 = (long long)by * 256 + wr * 128;
  const int ccol0 = bx * 256 + wc * 64;
#pragma unroll
  for (int n = 0; n < 4; ++n) {
    const int cg = ccol0 + n * 16 + l15;
#pragma unroll
    for (int m = 0; m < 8; ++m)
#pragma unroll
      for (int j = 0; j < 4; ++j) {
        const long long rg = crow0 + m * 16 + r4 + j;
        C[(long long)z * sCz + rg * ldc + cg] = (_Float16)(acc[m][n][j] * scale);
      }
  }
}

// ---------------------------------------------------------------------------
__global__ __launch_bounds__(256)
void cast_f32_bf16(const float* __restrict__ in, ushort_t* __restrict__ out, long long n)
{
  long long i = ((long long)blockIdx.x * blockDim.x + threadIdx.x) * 4;
  const long long stride = (long long)gridDim.x * blockDim.x * 4;
  for (; i < n; i += stride) {
    const float4 v = *(const float4*)&in[i];
    ushort4 o;
    o.x = f2bf(v.x); o.y = f2bf(v.y); o.z = f2bf(v.z); o.w = f2bf(v.w);
    *(ushort4*)&out[i] = o;
  }
}

__global__ __launch_bounds__(256)
void prep_w(const float* __restrict__ Wq, const float* __restrict__ Wk,
            const float* __restrict__ Wv, const float* __restrict__ bq,
            const float* __restrict__ bk, const float* __restrict__ bv,
            ushort_t* __restrict__ w3, float* __restrict__ bcat)
{
  const int which = blockIdx.x >> 10;
  const float* W = (which == 0) ? Wq : (which == 1) ? Wk : Wv;
  const long long i = ((long long)(blockIdx.x & 1023) * 256 + threadIdx.x) * 4;
  const float4 v = *(const float4*)&W[i];
  ushort4 o;
  o.x = f2bf(v.x); o.y = f2bf(v.y); o.z = f2bf(v.z); o.w = f2bf(v.w);
  *(ushort4*)&w3[(long long)which * 1024 * 1024 + i] = o;
  const int g = blockIdx.x * 256 + threadIdx.x;
  if (g < 3072) bcat[g] = (g < 1024) ? bq[g] : (g < 2048) ? bk[g - 1024] : bv[g - 2048];
}

// row softmax over 2048 fp16 -> bf16, one block (256 thr) per row
__global__ __launch_bounds__(256)
void softmax2048(const _Float16* __restrict__ Sc, ushort_t* __restrict__ P)
{
  const long long row = blockIdx.x;
  const _Float16* s = Sc + row * 2048;
  const int tid = threadIdx.x;
  const int wave = tid >> 6, lane = tid & 63;

  const h8 a = *(const h8*)&s[tid * 8];
  float f[8];
#pragma unroll
  for (int i = 0; i < 8; ++i) f[i] = (float)a[i];
  float m = fmaxf(fmaxf(fmaxf(f[0], f[1]), fmaxf(f[2], f[3])),
                  fmaxf(fmaxf(f[4], f[5]), fmaxf(f[6], f[7])));
#pragma unroll
  for (int off = 32; off > 0; off >>= 1) m = fmaxf(m, __shfl_xor(m, off));
  __shared__ float redm[4], reds[4];
  if (lane == 0) redm[wave] = m;
  __syncthreads();
  m = fmaxf(fmaxf(redm[0], redm[1]), fmaxf(redm[2], redm[3]));

  float e[8];
#pragma unroll
  for (int i = 0; i < 8; ++i) e[i] = __expf(f[i] - m);
  float sum = ((e[0] + e[1]) + (e[2] + e[3])) + ((e[4] + e[5]) + (e[6] + e[7]));
#pragma unroll
  for (int off = 32; off > 0; off >>= 1) sum += __shfl_xor(sum, off);
  if (lane == 0) reds[wave] = sum;
  __syncthreads();
  sum = (reds[0] + reds[1]) + (reds[2] + reds[3]);
  const float inv = 1.0f / sum;

  short8v o;
#pragma unroll
  for (int i = 0; i < 8; ++i) o[i] = (short)f2bf(e[i] * inv);
  *(short8v*)&P[row * 2048 + tid * 8] = o;
}

// ---------------------------------------------------------------------------
extern "C" void kernel_launch(void* const* d_in, const int* in_sizes, int n_in,
                              void* d_out, int out_size, void* d_ws, size_t ws_size,
                              hipStream_t stream)
{
  constexpr int B = 4, S = 2048, D = 1024;
  constexpr long long MT = (long long)B * S;
  constexpr long long SD = (long long)S * D;
  constexpr long long SS = (long long)S * S;

  const float* x  = (const float*)d_in[0];
  const float* Wq = (const float*)d_in[1];
  const float* bq = (const float*)d_in[2];
  const float* Wk = (const float*)d_in[3];
  const float* bk = (const float*)d_in[4];
  const float* Wv = (const float*)d_in[5];
  const float* bv = (const float*)d_in[6];
  float* out = (float*)d_out;

  // ws layout (bytes)
  char* base = (char*)d_ws;
  ushort_t*  q       = (ushort_t*)(base);               // 16777216
  ushort_t*  k       = (ushort_t*)(base + 16777216);    // 16777216
  ushort_t*  vt      = (ushort_t*)(base + 33554432);    // 16777216  [4][1024][2048]
  _Float16*  scores  = (_Float16*)(base + 50331648);    // 33554432  fp16
  ushort_t*  P       = (ushort_t*)(base + 117440512);   // 33554432
  ushort_t*  xb      = (ushort_t*)(base + 83886080);    // 16777216
  ushort_t*  w3      = (ushort_t*)(base + 100663296);   // 6291456
  float*     bcat    = (float*)   (base + 106954752);   // 12288

  // 1) casts
  cast_f32_bf16<<<2048, 256, 0, stream>>>(x, xb, MT * D);
  prep_w<<<3072, 256, 0, stream>>>(Wq, Wk, Wv, bq, bk, bv, w3, bcat);

  // 2) fused QKV projection -> q, k (plain) + vt (transposed), bias fused
  gemm128<2, 4, 8><<<dim3(24, 64, 1), 512, 0, stream>>>(
      xb, 0, D, w3, 0, D, q, k, vt, 0, 1024, D, 1.f, bcat);

  // 3) QK^T: scores[z] = (q @ k^T) / 32  (fp16 out)
  gemm256<<<dim3(8, 8, 4), 512, 0, stream>>>(
      q, SD, D, k, SD, D, scores, SS, S, D, 0.03125f);

  // 4) softmax rows (fp16 in, bf16 out)
  softmax2048<<<MT, 256, 0, stream>>>(scores, P);

  // 5) PV: out[z] = P @ vt^T
  gemm128<0, 2, 4><<<dim3(8, 16, 4), 512, 0, stream>>>(
      P, SS, S, vt, (long long)D * S, S, out, nullptr, nullptr, SD, D, S, 1.f, nullptr);
}

// Round 9
// 164.329 us; speedup vs baseline: 1.4712x; 1.0262x over previous
//
#include <hip/hip_runtime.h>

// Attention_13632226198096: B=4, S=2048, D=1024 fp32 single-head attention.
// Round 9: proj reverted to the m97 structure (128^2 tile, 256 thr, 32 KB
// LDS, simple 2-barrier loop, 4 blocks/CU -> cross-block overlap hides
// staging; r1 measured ~860 TF on this shape) + swizzle + fused q/k/vt
// epilogue. QK: 256^2 4-phase (r8). PV: 128^2 2-phase 2 blk/CU (r8, fenced).
// fp16 scores. Conflict-free row&7 XOR LDS swizzle everywhere.

typedef unsigned short ushort_t;
typedef __bf16 bf16x8 __attribute__((ext_vector_type(8)));
typedef float f32x4 __attribute__((ext_vector_type(4)));
typedef _Float16 h8 __attribute__((ext_vector_type(8)));
typedef short short8v __attribute__((ext_vector_type(8)));

__device__ __forceinline__ unsigned short f2bf(float f) {
  unsigned u = __builtin_bit_cast(unsigned, f);
  u += 0x7fffu + ((u >> 16) & 1u);
  return (unsigned short)(u >> 16);
}

// ---------------------------------------------------------------------------
// proj_gemm (m97 structure): C[8192,3072] = xb @ w3^T + bcat, split into
// q / k (row-major bf16) and vt (v transposed, [4][1024][2048]).
// 128x128 tile, BK=64, 256 thr = 4 waves (2x2), 32 KB LDS, 2-barrier loop.
// ---------------------------------------------------------------------------
__global__ __launch_bounds__(256, 4)
void proj_gemm(const ushort_t* __restrict__ A, int lda,
               const ushort_t* __restrict__ Bm, int ldb,
               ushort_t* __restrict__ Cq, ushort_t* __restrict__ Ck,
               ushort_t* __restrict__ Cvt, int K,
               const float* __restrict__ bias)
{
  __shared__ ushort_t smA[128 * 64] __attribute__((aligned(16)));
  __shared__ ushort_t smB[128 * 64] __attribute__((aligned(16)));

  constexpr int RX = 4, RY = 8, BPR = RX * RY;
  const int gx = gridDim.x;
  const int lin = blockIdx.y * gx + blockIdx.x;
  const int xcd = lin & 7, s = lin >> 3;
  const int chunk = s / BPR, idx = s % BPR;
  const int rect = chunk * 8 + xcd;
  const int nrx = gx / RX;
  const int bx = (rect % nrx) * RX + (idx % RX);
  const int by = (rect / nrx) * RY + (idx / RX);

  const int row0 = by * 128, col0 = bx * 128;

  const int tid = threadIdx.x;
  const int wave = tid >> 6, lane = tid & 63;
  const int wr = (wave >> 1) * 64, wc = (wave & 1) * 64;
  const int l15 = lane & 15;

  // staging: thread t -> row t>>3 (0..31, +i*32), swizzled col
  const int srow = tid >> 3;
  const int scol = ((tid & 7) ^ (srow & 7)) * 8;
  const ushort_t* ag = A  + (long long)(row0 + srow) * lda + scol;
  const ushort_t* bg = Bm + (long long)(col0 + srow) * ldb + scol;
  ushort_t* ldsA = &smA[(wave * 8) * 64];   // wave-uniform base
  ushort_t* ldsB = &smB[(wave * 8) * 64];

  f32x4 acc[4][4];
#pragma unroll
  for (int m = 0; m < 4; ++m)
#pragma unroll
    for (int n = 0; n < 4; ++n)
#pragma unroll
      for (int j = 0; j < 4; ++j) acc[m][n][j] = 0.f;

  for (int k0 = 0; k0 < K; k0 += 64) {
#pragma unroll
    for (int i = 0; i < 4; ++i) {
      __builtin_amdgcn_global_load_lds(
          (const __attribute__((address_space(1))) void*)(ag + (long long)i * 32 * lda + k0),
          (__attribute__((address_space(3))) void*)(ldsA + i * 32 * 64), 16, 0, 0);
      __builtin_amdgcn_global_load_lds(
          (const __attribute__((address_space(1))) void*)(bg + (long long)i * 32 * ldb + k0),
          (__attribute__((address_space(3))) void*)(ldsB + i * 32 * 64), 16, 0, 0);
    }
    __syncthreads();   // drains vmcnt + lgkm
#pragma unroll
    for (int kk = 0; kk < 2; ++kk) {
      const int kx = (((lane >> 4) + 4 * kk) ^ (l15 & 7)) * 8;
      bf16x8 af[4], bfv[4];
#pragma unroll
      for (int m = 0; m < 4; ++m)
        af[m] = *(const bf16x8*)&smA[(wr + m * 16 + l15) * 64 + kx];
#pragma unroll
      for (int n = 0; n < 4; ++n)
        bfv[n] = *(const bf16x8*)&smB[(wc + n * 16 + l15) * 64 + kx];
#pragma unroll
      for (int m = 0; m < 4; ++m)
#pragma unroll
        for (int n = 0; n < 4; ++n)
          acc[m][n] = __builtin_amdgcn_mfma_f32_16x16x32_bf16(af[m], bfv[n], acc[m][n], 0, 0, 0);
    }
    __syncthreads();
  }

  // epilogue: C/D layout col=lane&15, row=(lane>>4)*4+j; sel uniform/block
  const int r4 = (lane >> 4) * 4;
  const int sel = col0 >> 10;
#pragma unroll
  for (int n = 0; n < 4; ++n) {
    const int cg = col0 + wc + n * 16 + l15;
    const int col = cg & 1023;
    const float badd = bias[cg];
    if (sel < 2) {
      ushort_t* outp = (sel == 0) ? Cq : Ck;
#pragma unroll
      for (int m = 0; m < 4; ++m)
#pragma unroll
        for (int j = 0; j < 4; ++j) {
          const long long rg = row0 + wr + m * 16 + r4 + j;
          outp[rg * 1024 + col] = f2bf(acc[m][n][j] + badd);
        }
    } else {
#pragma unroll
      for (int m = 0; m < 4; ++m) {
        const long long rg = row0 + wr + m * 16 + r4;
        const long long b = rg >> 11, srw = rg & 2047;
        ushort4 o;
        o.x = f2bf(acc[m][n][0] + badd);
        o.y = f2bf(acc[m][n][1] + badd);
        o.z = f2bf(acc[m][n][2] + badd);
        o.w = f2bf(acc[m][n][3] + badd);
        *(ushort4*)&Cvt[b * 2097152 + (long long)col * 2048 + srw] = o;
      }
    }
  }
}

// ---------------------------------------------------------------------------
// pv_gemm: 128x128 tile, 2-phase, 64 KB LDS, 2 blocks/CU (r8 gemm128 MODE 0).
// ---------------------------------------------------------------------------
template<int RX, int RY>
__global__ __launch_bounds__(512, 4)
void pv_gemm(const ushort_t* __restrict__ A, long long sAz, int lda,
             const ushort_t* __restrict__ Bm, long long sBz, int ldb,
             float* __restrict__ C0, long long sCz, int ldc, int K)
{
  constexpr int SLOT = 8192;
  constexpr int BUF  = 2 * SLOT;
  __shared__ ushort_t lds_[2 * BUF] __attribute__((aligned(16)));

  constexpr int BPR = RX * RY;
  const int gx = gridDim.x;
  const int lin = blockIdx.y * gx + blockIdx.x;
  const int xcd = lin & 7, s = lin >> 3;
  const int chunk = s / BPR, idx = s % BPR;
  const int rect = chunk * 8 + xcd;
  const int nrx = gx / RX;
  const int bx = (rect % nrx) * RX + (idx % RX);
  const int by = (rect / nrx) * RY + (idx / RX);

  const int z = blockIdx.z;
  const ushort_t* Ab = A  + (long long)z * sAz + (long long)by * 128 * lda;
  const ushort_t* Bb = Bm + (long long)z * sBz + (long long)bx * 128 * ldb;

  const int tid = threadIdx.x, wid = tid >> 6, lane = tid & 63;
  const int wr = wid >> 2, wc = wid & 3;
  const int l15 = lane & 15;
  const int kx0 = (((lane >> 4) + 0) ^ (l15 & 7)) * 8;
  const int kx1 = (((lane >> 4) + 4) ^ (l15 & 7)) * 8;
  const int srow = lane >> 3;
  const int scol = ((lane & 7) ^ (srow & 7)) * 8;

  const ushort_t* agA = Ab + (long long)(wid * 8 + srow) * lda + scol;
  const ushort_t* agB = Bb + (long long)(wid * 8 + srow) * ldb + scol;
  const long long jA = (long long)64 * lda, jB = (long long)64 * ldb;
  const int ldsA0 = wid * 512;
  const int ldsB0 = SLOT + wid * 512;

  auto stage = [&](const ushort_t* g, long long jstep, int ldsOff) {
#pragma unroll
    for (int j = 0; j < 2; ++j)
      __builtin_amdgcn_global_load_lds(
          (const __attribute__((address_space(1))) void*)(g + j * jstep),
          (__attribute__((address_space(3))) void*)(&lds_[ldsOff + j * 4096]),
          16, 0, 0);
  };

  f32x4 acc[4][2];
#pragma unroll
  for (int m = 0; m < 4; ++m)
#pragma unroll
    for (int n = 0; n < 2; ++n)
#pragma unroll
      for (int j = 0; j < 4; ++j) acc[m][n][j] = 0.f;

  stage(agA, jA, 0 * BUF + ldsA0); agA += 64;
  stage(agB, jB, 0 * BUF + ldsB0); agB += 64;
  stage(agA, jA, 1 * BUF + ldsA0); agA += 64;
  stage(agB, jB, 1 * BUF + ldsB0); agB += 64;
  asm volatile("s_waitcnt vmcnt(4)" ::: "memory");
  __builtin_amdgcn_s_barrier();

  const int NT = K >> 6;
  bf16x8 a0[4], a1[4], bf[2];

  for (int t = 0; t < NT; ++t) {
    const int q = t & 1;
    const ushort_t* Al = &lds_[q * BUF] + wr * 4096;
    const ushort_t* Bl = &lds_[q * BUF + SLOT] + wc * 2048;

    // ph1: all A frags + B k0
#pragma unroll
    for (int m = 0; m < 4; ++m) a0[m] = *(const bf16x8*)(Al + (m * 16 + l15) * 64 + kx0);
#pragma unroll
    for (int n = 0; n < 2; ++n) bf[n] = *(const bf16x8*)(Bl + (n * 16 + l15) * 64 + kx0);
#pragma unroll
    for (int m = 0; m < 4; ++m) a1[m] = *(const bf16x8*)(Al + (m * 16 + l15) * 64 + kx1);
    __builtin_amdgcn_s_barrier();
    __builtin_amdgcn_s_setprio(1);
#pragma unroll
    for (int m = 0; m < 4; ++m)
#pragma unroll
      for (int n = 0; n < 2; ++n)
        acc[m][n] = __builtin_amdgcn_mfma_f32_16x16x32_bf16(a0[m], bf[n], acc[m][n], 0, 0, 0);
    __builtin_amdgcn_s_setprio(0);
    __builtin_amdgcn_s_barrier();

    // ph2: B k1; drain DS reads, THEN stage A(t+2)+B(t+2)
#pragma unroll
    for (int n = 0; n < 2; ++n) bf[n] = *(const bf16x8*)(Bl + (n * 16 + l15) * 64 + kx1);
    asm volatile("s_waitcnt lgkmcnt(0)" ::: "memory");
    __builtin_amdgcn_sched_barrier(0);
    if (t + 2 < NT) {
      stage(agA, jA, q * BUF + ldsA0); agA += 64;
      stage(agB, jB, q * BUF + ldsB0); agB += 64;
    }
    __builtin_amdgcn_s_barrier();
    __builtin_amdgcn_s_setprio(1);
#pragma unroll
    for (int m = 0; m < 4; ++m)
#pragma unroll
      for (int n = 0; n < 2; ++n)
        acc[m][n] = __builtin_amdgcn_mfma_f32_16x16x32_bf16(a1[m], bf[n], acc[m][n], 0, 0, 0);
    __builtin_amdgcn_s_setprio(0);
    if (t < NT - 2)       asm volatile("s_waitcnt vmcnt(4)" ::: "memory");
    else if (t == NT - 2) asm volatile("s_waitcnt vmcnt(0)" ::: "memory");
    __builtin_amdgcn_s_barrier();
  }

  const int r4 = (lane >> 4) * 4;
  const long long crow0 = (long long)by * 128 + wr * 64;
  const int ccol0 = bx * 128 + wc * 32;
#pragma unroll
  for (int n = 0; n < 2; ++n) {
    const int cg = ccol0 + n * 16 + l15;
#pragma unroll
    for (int m = 0; m < 4; ++m)
#pragma unroll
      for (int j = 0; j < 4; ++j) {
        const long long rg = crow0 + m * 16 + r4 + j;
        C0[(long long)z * sCz + rg * ldc + cg] = acc[m][n][j];
      }
  }
}

// ---------------------------------------------------------------------------
// qk_gemm: 256x256 tile, 4-phase; fp16 scores out (r8 gemm256).
// ---------------------------------------------------------------------------
__global__ __launch_bounds__(512, 1)
void qk_gemm(const ushort_t* __restrict__ A, long long sAz, int lda,
             const ushort_t* __restrict__ Bm, long long sBz, int ldb,
             _Float16* __restrict__ C, long long sCz, int ldc,
             int K, float scale)
{
  constexpr int AH = 8192, BH = 8192, BUF = 2 * AH + 2 * BH;
  constexpr int RX = 4, RY = 2, BPR = RX * RY;
  __shared__ ushort_t lds_[2 * BUF] __attribute__((aligned(16)));

  const int gx = gridDim.x;
  const int lin = blockIdx.y * gx + blockIdx.x;
  const int xcd = lin & 7, s = lin >> 3;
  const int chunk = s / BPR, idx = s % BPR;
  const int rect = chunk * 8 + xcd;
  const int nrx = gx / RX;
  const int bx = (rect % nrx) * RX + (idx % RX);
  const int by = (rect / nrx) * RY + (idx / RX);

  const int z = blockIdx.z;
  const ushort_t* Ab = A  + (long long)z * sAz + (long long)by * 256 * lda;
  const ushort_t* Bb = Bm + (long long)z * sBz + (long long)bx * 256 * ldb;

  const int tid = threadIdx.x, wid = tid >> 6, lane = tid & 63;
  const int wr = wid >> 2, wc = wid & 3;
  const int l15 = lane & 15;
  const int kx0 = (((lane >> 4) + 0) ^ (l15 & 7)) * 8;
  const int kx1 = (((lane >> 4) + 4) ^ (l15 & 7)) * 8;
  const int srow = lane >> 3;
  const int scol = ((lane & 7) ^ (srow & 7)) * 8;

  const ushort_t* agA = Ab + (long long)(wid * 16 + srow) * lda + scol;
  const ushort_t* agB = Bb + (long long)(wid * 16 + srow) * ldb + scol;

  auto stageA = [&](int q) {
#pragma unroll
    for (int h = 0; h < 2; ++h)
#pragma unroll
      for (int j = 0; j < 2; ++j)
        __builtin_amdgcn_global_load_lds(
            (const __attribute__((address_space(1))) void*)(agA + (long long)(h * 128 + j * 8) * lda),
            (__attribute__((address_space(3))) void*)
              (&lds_[q * BUF + h * AH + (wid * 128 + j * 64) * 8]),
            16, 0, 0);
  };
  auto stageB = [&](int q) {
#pragma unroll
    for (int h = 0; h < 2; ++h)
#pragma unroll
      for (int j = 0; j < 2; ++j)
        __builtin_amdgcn_global_load_lds(
            (const __attribute__((address_space(1))) void*)(agB + (long long)(h * 128 + j * 8) * ldb),
            (__attribute__((address_space(3))) void*)
              (&lds_[q * BUF + 2 * AH + h * BH + (wid * 128 + j * 64) * 8]),
            16, 0, 0);
  };

  f32x4 acc[8][4];
#pragma unroll
  for (int m = 0; m < 8; ++m)
#pragma unroll
    for (int n = 0; n < 4; ++n)
#pragma unroll
      for (int j = 0; j < 4; ++j) acc[m][n][j] = 0.f;

  stageA(0); stageB(0); agA += 64; agB += 64;
  stageA(1); stageB(1); agA += 64; agB += 64;
  asm volatile("s_waitcnt vmcnt(8)" ::: "memory");
  __builtin_amdgcn_s_barrier();

  const int NT = K >> 6;
  bf16x8 af[4], bf[4];

  for (int t = 0; t < NT; ++t) {
    const int q = t & 1;
    const ushort_t* Al = &lds_[q * BUF + wr * AH];
    const ushort_t* Bl = &lds_[q * BUF + 2 * AH + (wc >> 1) * BH + (wc & 1) * 4096];

    // ph1
#pragma unroll
    for (int n = 0; n < 4; ++n) bf[n] = *(const bf16x8*)(Bl + (n * 16 + l15) * 64 + kx0);
#pragma unroll
    for (int m = 0; m < 4; ++m) af[m] = *(const bf16x8*)(Al + (m * 16 + l15) * 64 + kx0);
    __builtin_amdgcn_s_barrier();
    __builtin_amdgcn_s_setprio(1);
#pragma unroll
    for (int m = 0; m < 4; ++m)
#pragma unroll
      for (int n = 0; n < 4; ++n)
        acc[m][n] = __builtin_amdgcn_mfma_f32_16x16x32_bf16(af[m], bf[n], acc[m][n], 0, 0, 0);
    __builtin_amdgcn_s_setprio(0);
    __builtin_amdgcn_s_barrier();

    // ph2
#pragma unroll
    for (int m = 0; m < 4; ++m) af[m] = *(const bf16x8*)(Al + ((4 + m) * 16 + l15) * 64 + kx0);
    __builtin_amdgcn_s_barrier();
    __builtin_amdgcn_s_setprio(1);
#pragma unroll
    for (int m = 0; m < 4; ++m)
#pragma unroll
      for (int n = 0; n < 4; ++n)
        acc[4 + m][n] = __builtin_amdgcn_mfma_f32_16x16x32_bf16(af[m], bf[n], acc[4 + m][n], 0, 0, 0);
    __builtin_amdgcn_s_setprio(0);
    __builtin_amdgcn_s_barrier();

    // ph3
#pragma unroll
    for (int n = 0; n < 4; ++n) bf[n] = *(const bf16x8*)(Bl + (n * 16 + l15) * 64 + kx1);
#pragma unroll
    for (int m = 0; m < 4; ++m) af[m] = *(const bf16x8*)(Al + (m * 16 + l15) * 64 + kx1);
    __builtin_amdgcn_s_barrier();
    __builtin_amdgcn_s_setprio(1);
#pragma unroll
    for (int m = 0; m < 4; ++m)
#pragma unroll
      for (int n = 0; n < 4; ++n)
        acc[m][n] = __builtin_amdgcn_mfma_f32_16x16x32_bf16(af[m], bf[n], acc[m][n], 0, 0, 0);
    __builtin_amdgcn_s_setprio(0);
    __builtin_amdgcn_s_barrier();

    // ph4 + staged prefetch after lgkm drain
#pragma unroll
    for (int m = 0; m < 4; ++m) af[m] = *(const bf16x8*)(Al + ((4 + m) * 16 + l15) * 64 + kx1);
    asm volatile("s_waitcnt lgkmcnt(0)" ::: "memory");
    __builtin_amdgcn_sched_barrier(0);
    if (t + 2 < NT) { stageA(q); stageB(q); agA += 64; agB += 64; }
    __builtin_amdgcn_s_barrier();
    __builtin_amdgcn_s_setprio(1);
#pragma unroll
    for (int m = 0; m < 4; ++m)
#pragma unroll
      for (int n = 0; n < 4; ++n)
        acc[4 + m][n] = __builtin_amdgcn_mfma_f32_16x16x32_bf16(af[m], bf[n], acc[4 + m][n], 0, 0, 0);
    __builtin_amdgcn_s_setprio(0);
    if (t < NT - 2)       asm volatile("s_waitcnt vmcnt(8)" ::: "memory");
    else if (t == NT - 2) asm volatile("s_waitcnt vmcnt(0)" ::: "memory");
    __builtin_amdgcn_s_barrier();
  }

  const int r4 = (lane >> 4) * 4;
  const long long crow0 = (long long)by * 256 + wr * 128;
  const int ccol0 = bx * 256 + wc * 64;
#pragma unroll
  for (int n = 0; n < 4; ++n) {
    const int cg = ccol0 + n * 16 + l15;
#pragma unroll
    for (int m = 0; m < 8; ++m)
#pragma unroll
      for (int j = 0; j < 4; ++j) {
        const long long rg = crow0 + m * 16 + r4 + j;
        C[(long long)z * sCz + rg * ldc + cg] = (_Float16)(acc[m][n][j] * scale);
      }
  }
}

// ---------------------------------------------------------------------------
__global__ __launch_bounds__(256)
void cast_f32_bf16(const float* __restrict__ in, ushort_t* __restrict__ out, long long n)
{
  long long i = ((long long)blockIdx.x * blockDim.x + threadIdx.x) * 4;
  const long long stride = (long long)gridDim.x * blockDim.x * 4;
  for (; i < n; i += stride) {
    const float4 v = *(const float4*)&in[i];
    ushort4 o;
    o.x = f2bf(v.x); o.y = f2bf(v.y); o.z = f2bf(v.z); o.w = f2bf(v.w);
    *(ushort4*)&out[i] = o;
  }
}

__global__ __launch_bounds__(256)
void prep_w(const float* __restrict__ Wq, const float* __restrict__ Wk,
            const float* __restrict__ Wv, const float* __restrict__ bq,
            const float* __restrict__ bk, const float* __restrict__ bv,
            ushort_t* __restrict__ w3, float* __restrict__ bcat)
{
  const int which = blockIdx.x >> 10;
  const float* W = (which == 0) ? Wq : (which == 1) ? Wk : Wv;
  const long long i = ((long long)(blockIdx.x & 1023) * 256 + threadIdx.x) * 4;
  const float4 v = *(const float4*)&W[i];
  ushort4 o;
  o.x = f2bf(v.x); o.y = f2bf(v.y); o.z = f2bf(v.z); o.w = f2bf(v.w);
  *(ushort4*)&w3[(long long)which * 1024 * 1024 + i] = o;
  const int g = blockIdx.x * 256 + threadIdx.x;
  if (g < 3072) bcat[g] = (g < 1024) ? bq[g] : (g < 2048) ? bk[g - 1024] : bv[g - 2048];
}

// row softmax over 2048 fp16 -> bf16, one block (256 thr) per row
__global__ __launch_bounds__(256)
void softmax2048(const _Float16* __restrict__ Sc, ushort_t* __restrict__ P)
{
  const long long row = blockIdx.x;
  const _Float16* s = Sc + row * 2048;
  const int tid = threadIdx.x;
  const int wave = tid >> 6, lane = tid & 63;

  const h8 a = *(const h8*)&s[tid * 8];
  float f[8];
#pragma unroll
  for (int i = 0; i < 8; ++i) f[i] = (float)a[i];
  float m = fmaxf(fmaxf(fmaxf(f[0], f[1]), fmaxf(f[2], f[3])),
                  fmaxf(fmaxf(f[4], f[5]), fmaxf(f[6], f[7])));
#pragma unroll
  for (int off = 32; off > 0; off >>= 1) m = fmaxf(m, __shfl_xor(m, off));
  __shared__ float redm[4], reds[4];
  if (lane == 0) redm[wave] = m;
  __syncthreads();
  m = fmaxf(fmaxf(redm[0], redm[1]), fmaxf(redm[2], redm[3]));

  float e[8];
#pragma unroll
  for (int i = 0; i < 8; ++i) e[i] = __expf(f[i] - m);
  float sum = ((e[0] + e[1]) + (e[2] + e[3])) + ((e[4] + e[5]) + (e[6] + e[7]));
#pragma unroll
  for (int off = 32; off > 0; off >>= 1) sum += __shfl_xor(sum, off);
  if (lane == 0) reds[wave] = sum;
  __syncthreads();
  sum = (reds[0] + reds[1]) + (reds[2] + reds[3]);
  const float inv = 1.0f / sum;

  short8v o;
#pragma unroll
  for (int i = 0; i < 8; ++i) o[i] = (short)f2bf(e[i] * inv);
  *(short8v*)&P[row * 2048 + tid * 8] = o;
}

// ---------------------------------------------------------------------------
extern "C" void kernel_launch(void* const* d_in, const int* in_sizes, int n_in,
                              void* d_out, int out_size, void* d_ws, size_t ws_size,
                              hipStream_t stream)
{
  constexpr int B = 4, S = 2048, D = 1024;
  constexpr long long MT = (long long)B * S;
  constexpr long long SD = (long long)S * D;
  constexpr long long SS = (long long)S * S;

  const float* x  = (const float*)d_in[0];
  const float* Wq = (const float*)d_in[1];
  const float* bq = (const float*)d_in[2];
  const float* Wk = (const float*)d_in[3];
  const float* bk = (const float*)d_in[4];
  const float* Wv = (const float*)d_in[5];
  const float* bv = (const float*)d_in[6];
  float* out = (float*)d_out;

  // ws layout (bytes)
  char* base = (char*)d_ws;
  ushort_t*  q       = (ushort_t*)(base);               // 16777216
  ushort_t*  k       = (ushort_t*)(base + 16777216);    // 16777216
  ushort_t*  vt      = (ushort_t*)(base + 33554432);    // 16777216  [4][1024][2048]
  _Float16*  scores  = (_Float16*)(base + 50331648);    // 33554432  fp16
  ushort_t*  P       = (ushort_t*)(base + 117440512);   // 33554432
  ushort_t*  xb      = (ushort_t*)(base + 83886080);    // 16777216
  ushort_t*  w3      = (ushort_t*)(base + 100663296);   // 6291456
  float*     bcat    = (float*)   (base + 106954752);   // 12288

  // 1) casts
  cast_f32_bf16<<<2048, 256, 0, stream>>>(x, xb, MT * D);
  prep_w<<<3072, 256, 0, stream>>>(Wq, Wk, Wv, bq, bk, bv, w3, bcat);

  // 2) fused QKV projection (m97 structure) -> q, k, vt(transposed)
  proj_gemm<<<dim3(24, 64, 1), 256, 0, stream>>>(
      xb, D, w3, D, q, k, vt, D, bcat);

  // 3) QK^T: scores[z] = (q @ k^T) / 32  (fp16 out)
  qk_gemm<<<dim3(8, 8, 4), 512, 0, stream>>>(
      q, SD, D, k, SD, D, scores, SS, S, D, 0.03125f);

  // 4) softmax rows (fp16 in, bf16 out)
  softmax2048<<<MT, 256, 0, stream>>>(scores, P);

  // 5) PV: out[z] = P @ vt^T
  pv_gemm<2, 4><<<dim3(8, 16, 4), 512, 0, stream>>>(
      P, SS, S, vt, (long long)D * S, S, out, SD, D, S);
}